// Round 16
// baseline (9788.808 us; speedup 1.0000x reference)
//
#include <hip/hip_runtime.h>

static constexpr int Bn = 8192;
// output element offsets (FLOAT32 elements)
static constexpr size_t XR_OFF = 0;
static constexpr size_t ZL_OFF = 8388608;
static constexpr size_t ZR_OFF = 12582912;
static constexpr size_t ZI_OFF = 16777216;
static constexpr size_t OT_OFF = 20971520;
static constexpr size_t XO_OFF = 20971521;
static constexpr size_t CT_OFF = 29360129;
static constexpr size_t LG_OFF = 29360130;
static constexpr size_t SB_OFF = 20971522;   // scratch inside f32 x_ori region

// ---- threefry2x32 core (KAT-verified) ----
__device__ __forceinline__ void tf2x32(unsigned k0, unsigned k1, unsigned& x0, unsigned& x1) {
  const unsigned ks[3] = {k0, k1, k0 ^ k1 ^ 0x1BD11BDAu};
  x0 += ks[0]; x1 += ks[1];
  const int R1r[4] = {13, 15, 26, 6}, R2r[4] = {17, 29, 16, 24};
#pragma unroll
  for (int g = 0; g < 5; ++g) {
    const int* rr = (g & 1) ? R2r : R1r;
#pragma unroll
    for (int q = 0; q < 4; ++q) {
      x0 += x1;
      x1 = (x1 << rr[q]) | (x1 >> (32 - rr[q]));
      x1 ^= x0;
    }
    x0 += ks[(g + 1) % 3];
    x1 += ks[(g + 2) % 3] + (unsigned)(g + 1);
  }
}

// ---- transpose f32 [R][C] -> f32 [C][R] ----
__global__ __launch_bounds__(256) void transpose_k(const float* __restrict__ in,
                                                   float* __restrict__ out,
                                                   int R, int C) {
  __shared__ float t[32][33];
  int c0 = blockIdx.x * 32, r0 = blockIdx.y * 32;
  int lc = threadIdx.x & 31, lr = threadIdx.x >> 5;
#pragma unroll
  for (int i = 0; i < 4; ++i) {
    int r = lr + i * 8;
    t[r][lc] = in[(size_t)(r0 + r) * C + c0 + lc];
  }
  __syncthreads();
#pragma unroll
  for (int i = 0; i < 4; ++i) {
    int cc = lr + i * 8;
    out[(size_t)(c0 + cc) * R + r0 + lc] = t[lc][cc];
  }
}

// ---- f32 tiled GEMM: C[M,N] = act(A[M,K] @ BT[N,K]^T + bias) ----
// AMODE 1: A = f32 pointer + element offset. AMODE 2: row r of A = concat(zr[prm[r]], zi[ord[r]]).
template <int ACT, int AMODE>
__global__ __launch_bounds__(256) void gemm_k(const float* __restrict__ A, size_t aoff,
                                              const float* __restrict__ BT,
                                              const float* __restrict__ bias,
                                              float* __restrict__ Cc,
                                              int M, int N, int K,
                                              const int* __restrict__ prmq,
                                              const int* __restrict__ ordq,
                                              const float* __restrict__ zr,
                                              const float* __restrict__ zi) {
  __shared__ float As[64][17];
  __shared__ float Bs[64][17];
  const int t = threadIdx.x;
  const int row0 = blockIdx.y * 64, col0 = blockIdx.x * 64;
  const int lr = t >> 2;
  const int lk4 = (t & 3) * 4;
  const int tr = t >> 4, tc = t & 15;
  float acc[4][4] = {};

  int ga = row0 + lr; ga = ga < M ? ga : M - 1;
  int gb = col0 + lr; gb = gb < N ? gb : N - 1;
  int pidx = 0, oidx = 0;
  if (AMODE == 2) {
    pidx = prmq[ga]; pidx = pidx < 0 ? 0 : (pidx > Bn - 1 ? Bn - 1 : pidx);
    oidx = ordq[ga]; oidx = oidx < 0 ? 0 : (oidx > Bn - 1 ? Bn - 1 : oidx);
  }

  for (int k0 = 0; k0 < K; k0 += 16) {
#pragma unroll
    for (int q = 0; q < 4; ++q) {
      int kk = k0 + lk4 + q;
      float av;
      if (AMODE == 1) av = A[aoff + (size_t)ga * K + kk];
      else av = (kk < 512) ? zr[(size_t)pidx * 512 + kk]
                           : zi[(size_t)oidx * 512 + (kk - 512)];
      As[lr][lk4 + q] = av;
      Bs[lr][lk4 + q] = BT[(size_t)gb * K + kk];
    }
    __syncthreads();
#pragma unroll
    for (int kk = 0; kk < 16; ++kk) {
      float av[4], bv[4];
#pragma unroll
      for (int i = 0; i < 4; ++i) av[i] = As[tr * 4 + i][kk];
#pragma unroll
      for (int j = 0; j < 4; ++j) bv[j] = Bs[tc * 4 + j][kk];
#pragma unroll
      for (int i = 0; i < 4; ++i)
#pragma unroll
        for (int j = 0; j < 4; ++j) acc[i][j] += av[i] * bv[j];
    }
    __syncthreads();
  }

#pragma unroll
  for (int i = 0; i < 4; ++i) {
    int r = row0 + tr * 4 + i;
    if (r >= M) break;
#pragma unroll
    for (int j = 0; j < 4; ++j) {
      int c = col0 + tc * 4 + j;
      if (c < N) {
        float v = acc[i][j] + bias[c];
        if (ACT == 1) v = (v >= 0.f) ? v : 0.01f * v;
        Cc[(size_t)r * N + c] = v;
      }
    }
  }
}

// ---- z_label[b][:] = zE[labels[b]][:] ----
__global__ __launch_bounds__(256) void gather512_k(const float* __restrict__ zE,
                                                   const int* __restrict__ labels,
                                                   float* __restrict__ dst) {
  int b = blockIdx.x * 4 + (threadIdx.x >> 6);
  int ln = threadIdx.x & 63;
  int g = labels[b]; g = g < 0 ? 0 : (g > 31 ? 31 : g);
#pragma unroll
  for (int q = 0; q < 8; ++q)
    dst[(size_t)b * 512 + ln * 8 + q] = zE[(size_t)g * 512 + ln * 8 + q];
}

// ---- partitionable threefry (jax>=0.4.30 default): bits[i] = o0^o1, counter (0, i) ----
__global__ __launch_bounds__(256) void threefry_s_k(const int* __restrict__ labels,
                                                    float* __restrict__ s) {
  int i = blockIdx.x * blockDim.x + threadIdx.x;
  if (i >= Bn) return;
  unsigned x0 = 0u, x1 = (unsigned)i;
  tf2x32(0u, 1234u, x0, x1);
  unsigned bits = x0 ^ x1;
  float u = __uint_as_float((bits >> 9) | 0x3f800000u) - 1.0f;
  u = fmaxf(u, 0.0f);
  s[i] = (float)labels[i] + u;
}

__global__ __launch_bounds__(256) void hist_k(const int* __restrict__ labels,
                                              int* __restrict__ baseOff) {
  __shared__ int bins[32];
  if (threadIdx.x < 32) bins[threadIdx.x] = 0;
  __syncthreads();
  for (int i = threadIdx.x; i < Bn; i += 256) {
    int g = labels[i]; g = g < 0 ? 0 : (g > 31 ? 31 : g);
    atomicAdd(&bins[g], 1);
  }
  __syncthreads();
  if (threadIdx.x == 0) {
    int acc = 0;
    for (int g = 0; g < 32; ++g) { baseOff[g] = acc; acc += bins[g]; }
  }
}

__global__ __launch_bounds__(256) void rank_k(const int* __restrict__ labels,
                                              const float* __restrict__ s,
                                              const int* __restrict__ baseOff,
                                              int* __restrict__ order,
                                              int* __restrict__ perm) {
  int i = blockIdx.x * blockDim.x + threadIdx.x;
  int li = labels[i];
  float si = s[i];
  int ro = 0, rp = 0;
  for (int j = 0; j < Bn; ++j) {
    int lj = labels[j];
    float sj = s[j];
    bool same = (lj == li);
    ro += (same && (j < i)) ? 1 : 0;
    rp += (same && (sj < si || (sj == si && j < i))) ? 1 : 0;
  }
  int base = baseOff[li < 0 ? 0 : (li > 31 ? 31 : li)];
  int io = base + ro; io = io < 0 ? 0 : (io > Bn - 1 ? Bn - 1 : io);
  int ip = base + rp; ip = ip < 0 ? 0 : (ip > Bn - 1 ? Bn - 1 : ip);
  order[io] = i;
  perm[ip] = i;
}

// ---- per-sample cost*T (IPOT) and softplus(1.5*(cos_neg-cos_pos)) ----
__global__ __launch_bounds__(256) void persample_k(const float* __restrict__ out,
                                                   float* __restrict__ costT,
                                                   float* __restrict__ psamp) {
  int b = blockIdx.x * 4 + (threadIdx.x >> 6);
  int ln = threadIdx.x & 63;
  float dlr = 0.f, dli = 0.f, nl = 0.f, nr = 0.f, ni = 0.f;
#pragma unroll
  for (int q = 0; q < 8; ++q) {
    size_t idx = (size_t)b * 512 + ln * 8 + q;
    float fl = out[ZL_OFF + idx];
    float fr = out[ZR_OFF + idx];
    float fi = out[ZI_OFF + idx];
    dlr += fl * fr; dli += fl * fi;
    nl += fl * fl;  nr += fr * fr;  ni += fi * fi;
  }
#pragma unroll
  for (int off = 32; off; off >>= 1) {
    dlr += __shfl_down(dlr, off);
    dli += __shfl_down(dli, off);
    nl  += __shfl_down(nl,  off);
    nr  += __shfl_down(nr,  off);
    ni  += __shfl_down(ni,  off);
  }
  if (ln == 0) {
    float snl = sqrtf(nl), snr = sqrtf(nr), sni = sqrtf(ni);
    float cost = 1.0f - dlr / (fmaxf(snl, 1e-5f) * fmaxf(snr, 1e-5f));
    float cp = dlr / (fmaxf(snl, 1e-8f) * fmaxf(snr, 1e-8f));
    float cn = dli / (fmaxf(snl, 1e-8f) * fmaxf(sni, 1e-8f));
    float d = 1.5f * (cn - cp);
    float ps = (d > 0.f) ? d + log1pf(expf(-d)) : log1pf(expf(d));
    float a = expf(-cost * 2.0f), sg = 1.f, T = 1.f;
    for (int t = 0; t < 50; ++t) {
      float q = a * T;
      float dl = 1.f / (q * sg);
      sg = 1.f / (dl * q);
      T = dl * q * sg;
    }
    costT[b] = cost * T;
    psamp[b] = ps;
  }
}

__global__ __launch_bounds__(256) void ot_reduce_k(const float* __restrict__ costT,
                                                   float* __restrict__ out) {
  __shared__ float red[256];
  float sum = 0.f;
  for (int i = threadIdx.x; i < Bn; i += 256) sum += costT[i];
  red[threadIdx.x] = sum;
  __syncthreads();
  for (int st = 128; st; st >>= 1) {
    if (threadIdx.x < st) red[threadIdx.x] += red[threadIdx.x + st];
    __syncthreads();
  }
  if (threadIdx.x == 0) out[OT_OFF] = red[0] / (float)Bn;
}

__global__ __launch_bounds__(256) void group_reduce_k(const int* __restrict__ labels,
                                                      const float* __restrict__ psamp,
                                                      float* __restrict__ gmean,
                                                      float* __restrict__ present) {
  int g = blockIdx.x;
  __shared__ float rs[256];
  __shared__ int rc[256];
  float s = 0.f; int c = 0;
  for (int i = threadIdx.x; i < Bn; i += 256)
    if (labels[i] == g) { s += psamp[i]; c++; }
  rs[threadIdx.x] = s; rc[threadIdx.x] = c;
  __syncthreads();
  for (int st = 128; st; st >>= 1) {
    if (threadIdx.x < st) { rs[threadIdx.x] += rs[threadIdx.x + st]; rc[threadIdx.x] += rc[threadIdx.x + st]; }
    __syncthreads();
  }
  if (threadIdx.x == 0) {
    gmean[g] = rc[0] > 0 ? rs[0] / (float)rc[0] : 0.f;
    present[g] = rc[0] > 0 ? 1.f : 0.f;
  }
}

__global__ void contra_final_k(const float* __restrict__ gmean,
                               const float* __restrict__ present,
                               float* __restrict__ out) {
  if (threadIdx.x == 0) {
    float s = 0.f, p = 0.f;
    for (int g = 0; g < 32; ++g) { s += gmean[g]; p += present[g]; }
    out[CT_OFF] = s / p;
  }
}

// ---- x_ori[j] = x[order[j]] (runs LAST; overwrites scratch zone) ----
__global__ __launch_bounds__(128) void xori_k(const float* __restrict__ x,
                                              const int* __restrict__ order,
                                              float* __restrict__ out) {
  int j = blockIdx.x, t = threadIdx.x;
  int o = order[j]; o = o < 0 ? 0 : (o > Bn - 1 ? Bn - 1 : o);
#pragma unroll
  for (int q = 0; q < 8; ++q)
    out[XO_OFF + (size_t)j * 1024 + t * 8 + q] = x[(size_t)o * 1024 + t * 8 + q];
}

// ---- BN partial sums over one 1024-row chunk ----
__global__ __launch_bounds__(256) void bnacc_k(const float* __restrict__ h,
                                               float* __restrict__ sum,
                                               float* __restrict__ sum2) {
  int colbase = blockIdx.x * 64;
  int lc = threadIdx.x & 63, rg = threadIdx.x >> 6;
  float s = 0.f, s2 = 0.f;
  for (int r = rg; r < 1024; r += 4) {
    float v = h[(size_t)r * 2048 + colbase + lc];
    s += v; s2 += v * v;
  }
  __shared__ float sh[4][64], sh2[4][64];
  sh[rg][lc] = s; sh2[rg][lc] = s2;
  __syncthreads();
  if (rg == 0) {
    s  = sh[0][lc] + sh[1][lc] + sh[2][lc] + sh[3][lc];
    s2 = sh2[0][lc] + sh2[1][lc] + sh2[2][lc] + sh2[3][lc];
    sum[colbase + lc]  = s;
    sum2[colbase + lc] = s2;
  }
}

__global__ __launch_bounds__(256) void bnfinal_k(const float* __restrict__ sumA,
                                                 const float* __restrict__ sum2A,
                                                 const float* __restrict__ gamma,
                                                 const float* __restrict__ beta,
                                                 float* __restrict__ scale,
                                                 float* __restrict__ shift) {
  int c = blockIdx.x * 256 + threadIdx.x;   // 8 blocks -> 2048 cols
  float s = 0.f, s2 = 0.f;
  for (int q = 0; q < 8; ++q) { s += sumA[q * 2048 + c]; s2 += sum2A[q * 2048 + c]; }
  float mu = s / (float)Bn;
  float var = s2 / (float)Bn - mu * mu;
  float sc = gamma[c] / sqrtf(var + 1e-5f);
  scale[c] = sc;
  shift[c] = beta[c] - mu * sc;
}

// ---- BN apply + leaky, in place on one 1024x2048 chunk ----
__global__ __launch_bounds__(256) void bnapply_k(float* __restrict__ h,
                                                 const float* __restrict__ scale,
                                                 const float* __restrict__ shift) {
  size_t i = (size_t)blockIdx.x * 256 + threadIdx.x;   // x8 over 2,097,152 elems
#pragma unroll
  for (int q = 0; q < 8; ++q) {
    size_t e = i * 8 + q;
    int col = (int)(e & 2047);
    float f = h[e] * scale[col] + shift[col];
    f = (f >= 0.f) ? f : 0.01f * f;
    h[e] = f;
  }
}

__global__ void marker_k(float* __restrict__ p, float v) {
  if (threadIdx.x == 0) *p = v;
}

// ==================================================================================
extern "C" void kernel_launch(void* const* d_in, const int* in_sizes, int n_in,
                              void* d_out, int out_size, void* d_ws, size_t ws_size,
                              hipStream_t stream) {
  const float* x    = (const float*)d_in[0];
  const int*  labels = (const int*)d_in[1];
  const float* Wr1 = (const float*)d_in[2];  const float* br1 = (const float*)d_in[3];
  const float* Wr2 = (const float*)d_in[4];  const float* br2 = (const float*)d_in[5];
  const float* Wi1 = (const float*)d_in[6];  const float* bi1 = (const float*)d_in[7];
  const float* Wi2 = (const float*)d_in[8];  const float* bi2 = (const float*)d_in[9];
  const float* E   = (const float*)d_in[10];
  const float* Wd1 = (const float*)d_in[11]; const float* bd1 = (const float*)d_in[12];
  const float* Wd2 = (const float*)d_in[13]; const float* bd2 = (const float*)d_in[14];
  const float* Wc1 = (const float*)d_in[15]; const float* bc1 = (const float*)d_in[16];
  const float* bng = (const float*)d_in[17]; const float* bnb = (const float*)d_in[18];
  const float* Wc2 = (const float*)d_in[19]; const float* bc2 = (const float*)d_in[20];

  float* out = (float*)d_out;
  dim3 b256(256);
  const int* ni = nullptr;
  const float* nf = nullptr;

  if (ws_size < (1u << 20)) {
    marker_k<<<dim3(1), dim3(64), 0, stream>>>(out + XR_OFF, 110.f);
    return;
  }

  // ---- ws aux (~614 KB) ----
  char* wsb = (char*)d_ws;
  float* sval   = (float*)(wsb);            // 32 KB
  float* costT  = (float*)(wsb + 32768);
  float* psamp  = (float*)(wsb + 65536);
  int*   ordr   = (int*)  (wsb + 98304);
  int*   prm    = (int*)  (wsb + 131072);
  int*   baseOff= (int*)  (wsb + 163840);
  float* gmean  = (float*)(wsb + 164096);
  float* present= (float*)(wsb + 164224);
  float* bnscale= (float*)(wsb + 164352);   // 8 KB
  float* bnshift= (float*)(wsb + 172544);   // 8 KB
  float* bnsum  = (float*)(wsb + 180736);   // 8 slots x 2048 = 64 KB
  float* bnsum2 = (float*)(wsb + 246272);   // 64 KB
  float* hE     = (float*)(wsb + 311808);   // 32x2048 = 256 KB
  float* zE     = (float*)(wsb + 573952);   // 32x512 = 64 KB

  // ---- f32 scratch inside x_ori region [20971522, 27262978) ----
  float* TA   = out + SB_OFF;            // up to 2048x1024
  float* TB   = out + SB_OFF + 2097152;  // up to 1024x2048
  float* hbuf = out + SB_OFF + 4194304;  // 1024x2048

  // ---- encoder_r (8 chunks of 1024 rows) ----
  transpose_k<<<dim3(64, 32), b256, 0, stream>>>(Wr1, TA, 1024, 2048);   // [2048][1024]
  transpose_k<<<dim3(16, 64), b256, 0, stream>>>(Wr2, TB, 2048, 512);    // [512][2048]
  for (int mc = 0; mc < 8; ++mc) {
    gemm_k<1,1><<<dim3(32, 16), b256, 0, stream>>>(x, (size_t)mc * 1048576, TA, br1,
                                                   hbuf, 1024, 2048, 1024, ni, ni, nf, nf);
    gemm_k<0,1><<<dim3(8, 16), b256, 0, stream>>>(hbuf, 0, TB, br2,
                                                  out + ZR_OFF + (size_t)mc * 524288,
                                                  1024, 512, 2048, ni, ni, nf, nf);
  }
  // ---- label encoder + gather ----
  gemm_k<1,1><<<dim3(32, 1), b256, 0, stream>>>(E, 0, TA, br1, hE, 32, 2048, 1024, ni, ni, nf, nf);
  gemm_k<0,1><<<dim3(8, 1), b256, 0, stream>>>(hE, 0, TB, br2, zE, 32, 512, 2048, ni, ni, nf, nf);
  gather512_k<<<dim3(2048), b256, 0, stream>>>(zE, labels, out + ZL_OFF);

  // ---- encoder_i ----
  transpose_k<<<dim3(64, 32), b256, 0, stream>>>(Wi1, TA, 1024, 2048);
  transpose_k<<<dim3(16, 64), b256, 0, stream>>>(Wi2, TB, 2048, 512);
  for (int mc = 0; mc < 8; ++mc) {
    gemm_k<1,1><<<dim3(32, 16), b256, 0, stream>>>(x, (size_t)mc * 1048576, TA, bi1,
                                                   hbuf, 1024, 2048, 1024, ni, ni, nf, nf);
    gemm_k<0,1><<<dim3(8, 16), b256, 0, stream>>>(hbuf, 0, TB, bi2,
                                                  out + ZI_OFF + (size_t)mc * 524288,
                                                  1024, 512, 2048, ni, ni, nf, nf);
  }

  // ---- permutations + per-sample losses ----
  threefry_s_k<<<dim3(32), b256, 0, stream>>>(labels, sval);
  hist_k<<<dim3(1), b256, 0, stream>>>(labels, baseOff);
  rank_k<<<dim3(32), b256, 0, stream>>>(labels, sval, baseOff, ordr, prm);
  persample_k<<<dim3(2048), b256, 0, stream>>>(out, costT, psamp);
  group_reduce_k<<<dim3(32), b256, 0, stream>>>(labels, psamp, gmean, present);

  // ---- decoder (gather fused into L1 A-loads) ----
  transpose_k<<<dim3(64, 32), b256, 0, stream>>>(Wd1, TA, 1024, 2048);   // [2048][1024]
  transpose_k<<<dim3(32, 64), b256, 0, stream>>>(Wd2, TB, 2048, 1024);   // [1024][2048]
  for (int mc = 0; mc < 8; ++mc) {
    gemm_k<1,2><<<dim3(32, 16), b256, 0, stream>>>(
        nf, 0, TA, bd1, hbuf, 1024, 2048, 1024,
        prm + mc * 1024, ordr + mc * 1024, out + ZR_OFF, out + ZI_OFF);
    gemm_k<0,1><<<dim3(16, 16), b256, 0, stream>>>(hbuf, 0, TB, bd2,
                                                   out + XR_OFF + (size_t)mc * 1048576,
                                                   1024, 1024, 2048, ni, ni, nf, nf);
  }

  // ---- classifier (two passes over 1024-row chunks) ----
  transpose_k<<<dim3(64, 16), b256, 0, stream>>>(Wc1, TA, 512, 2048);    // [2048][512]
  transpose_k<<<dim3(1, 64), b256, 0, stream>>>(Wc2, TB, 2048, 32);      // [32][2048]
  for (int mc = 0; mc < 8; ++mc) {
    gemm_k<0,1><<<dim3(32, 16), b256, 0, stream>>>(out, ZR_OFF + (size_t)mc * 524288,
                                                   TA, bc1, hbuf, 1024, 2048, 512, ni, ni, nf, nf);
    bnacc_k<<<dim3(32), b256, 0, stream>>>(hbuf, bnsum + mc * 2048, bnsum2 + mc * 2048);
  }
  bnfinal_k<<<dim3(8), b256, 0, stream>>>(bnsum, bnsum2, bng, bnb, bnscale, bnshift);
  for (int mc = 0; mc < 8; ++mc) {
    gemm_k<0,1><<<dim3(32, 16), b256, 0, stream>>>(out, ZR_OFF + (size_t)mc * 524288,
                                                   TA, bc1, hbuf, 1024, 2048, 512, ni, ni, nf, nf);
    bnapply_k<<<dim3(1024), b256, 0, stream>>>(hbuf, bnscale, bnshift);
    gemm_k<0,1><<<dim3(1, 16), b256, 0, stream>>>(hbuf, 0, TB, bc2,
                                                  out + LG_OFF + (size_t)mc * 32768,
                                                  1024, 32, 2048, ni, ni, nf, nf);
  }

  // ---- scalar finals, then x_ori gather LAST (kills scratch zone) ----
  ot_reduce_k<<<dim3(1), b256, 0, stream>>>(costT, out);
  contra_final_k<<<dim3(1), dim3(64), 0, stream>>>(gmean, present, out);
  xori_k<<<dim3(8192), dim3(128), 0, stream>>>(x, ordr, out);

  (void)in_sizes; (void)n_in; (void)out_size;
}

// Round 17
// 2912.790 us; speedup vs baseline: 3.3606x; 3.3606x over previous
//
#include <hip/hip_runtime.h>

typedef short  s16x8 __attribute__((ext_vector_type(8)));
typedef __bf16 bf16x8 __attribute__((ext_vector_type(8)));
typedef float  f32x4 __attribute__((ext_vector_type(4)));

static constexpr int Bn = 8192;
// output element offsets (FLOAT32 elements)
static constexpr size_t XR_OFF = 0;
static constexpr size_t ZL_OFF = 8388608;
static constexpr size_t ZR_OFF = 12582912;
static constexpr size_t ZI_OFF = 16777216;
static constexpr size_t OT_OFF = 20971520;
static constexpr size_t XO_OFF = 20971521;
static constexpr size_t CT_OFF = 29360129;
static constexpr size_t LG_OFF = 29360130;
static constexpr size_t SB_OFF = 20971522;   // scratch zone inside f32 x_ori region

// ---- threefry2x32 core ----
__device__ __forceinline__ void tf2x32(unsigned k0, unsigned k1, unsigned& x0, unsigned& x1) {
  const unsigned ks[3] = {k0, k1, k0 ^ k1 ^ 0x1BD11BDAu};
  x0 += ks[0]; x1 += ks[1];
  const int R1r[4] = {13, 15, 26, 6}, R2r[4] = {17, 29, 16, 24};
#pragma unroll
  for (int g = 0; g < 5; ++g) {
    const int* rr = (g & 1) ? R2r : R1r;
#pragma unroll
    for (int q = 0; q < 4; ++q) {
      x0 += x1;
      x1 = (x1 << rr[q]) | (x1 >> (32 - rr[q]));
      x1 ^= x0;
    }
    x0 += ks[(g + 1) % 3];
    x1 += ks[(g + 2) % 3] + (unsigned)(g + 1);
  }
}

// ---- transpose f32 [R][C] -> bf16 [C][R] ----
__global__ __launch_bounds__(256) void transpose_k(const float* __restrict__ in,
                                                   __bf16* __restrict__ out,
                                                   int R, int C) {
  __shared__ float t[32][33];
  int c0 = blockIdx.x * 32, r0 = blockIdx.y * 32;
  int lc = threadIdx.x & 31, lr = threadIdx.x >> 5;
#pragma unroll
  for (int i = 0; i < 4; ++i) {
    int r = lr + i * 8;
    t[r][lc] = in[(size_t)(r0 + r) * C + c0 + lc];
  }
  __syncthreads();
#pragma unroll
  for (int i = 0; i < 4; ++i) {
    int cc = lr + i * 8;
    out[(size_t)(c0 + cc) * R + r0 + lc] = (__bf16)t[lc][cc];
  }
}

// ---- MFMA GEMM: C[M,N] = act(A[M,K] @ BT[N,K]^T + bias) ----
// 128x128 tile, BK=32, 4 waves (2x2), 4x4 frags of mfma_f32_16x16x32_bf16 per wave.
// AMODE: 0 = A bf16 (+elem offset); 1 = A f32 (+elem offset, converted while staging);
//        2 = decoder gather: row r = concat(zr_f32[prm[r]], zi_f32[ord[r]])
// OSEL : 0 = store f32; 1 = store bf16
template <int ACT, int AMODE, int OSEL>
__global__ __launch_bounds__(256) void mgemm_k(const void* __restrict__ A, size_t aoff,
                                               const __bf16* __restrict__ BT,
                                               const float* __restrict__ bias,
                                               void* __restrict__ Cc,
                                               int M, int N, int K,
                                               const int* __restrict__ prmq,
                                               const int* __restrict__ ordq,
                                               const float* __restrict__ zr,
                                               const float* __restrict__ zi) {
  __shared__ __bf16 As[128][32];
  __shared__ __bf16 Bs[128][32];
  const int tid = threadIdx.x;
  const int wv = tid >> 6, ln = tid & 63;
  const int row0 = blockIdx.y * 128, col0 = blockIdx.x * 128;
  const int wr = wv >> 1, wc = wv & 1;
  const int lrow = ln & 15;
  const int kgrp = (ln >> 4) * 8;
  const int srow = tid >> 1;          // staging row 0..127
  const int skh  = (tid & 1) * 16;    // staging k-half 0/16

  f32x4 acc[4][4] = {};

  int ga = row0 + srow; ga = ga < M ? ga : M - 1;
  int gb = col0 + srow; gb = gb < N ? gb : N - 1;
  int pidx = 0, oidx = 0;
  if (AMODE == 2) {
    pidx = prmq[ga]; pidx = pidx < 0 ? 0 : (pidx > Bn - 1 ? Bn - 1 : pidx);
    oidx = ordq[ga]; oidx = oidx < 0 ? 0 : (oidx > Bn - 1 ? Bn - 1 : oidx);
  }

  for (int k0 = 0; k0 < K; k0 += 32) {
    const int kk = k0 + skh;
    // ---- stage A half-row (16 elems) ----
    bf16x8 alo, ahi;
    if (AMODE == 0) {
      const __bf16* Ab = (const __bf16*)A + aoff + (size_t)ga * K + kk;
      alo = *(const bf16x8*)Ab;
      ahi = *(const bf16x8*)(Ab + 8);
    } else {
      const float* Af;
      if (AMODE == 1) Af = (const float*)A + aoff + (size_t)ga * K + kk;
      else Af = (kk < 512) ? (zr + (size_t)pidx * 512 + kk)
                           : (zi + (size_t)oidx * 512 + (kk - 512));
      f32x4 v0 = *(const f32x4*)(Af + 0);
      f32x4 v1 = *(const f32x4*)(Af + 4);
      f32x4 v2 = *(const f32x4*)(Af + 8);
      f32x4 v3 = *(const f32x4*)(Af + 12);
#pragma unroll
      for (int q = 0; q < 4; ++q) { alo[q] = (__bf16)v0[q]; alo[q + 4] = (__bf16)v1[q]; }
#pragma unroll
      for (int q = 0; q < 4; ++q) { ahi[q] = (__bf16)v2[q]; ahi[q + 4] = (__bf16)v3[q]; }
    }
    *(bf16x8*)&As[srow][skh]     = alo;
    *(bf16x8*)&As[srow][skh + 8] = ahi;
    // ---- stage B half-row (already bf16) ----
    {
      const __bf16* Bb = BT + (size_t)gb * K + kk;
      *(bf16x8*)&Bs[srow][skh]     = *(const bf16x8*)Bb;
      *(bf16x8*)&Bs[srow][skh + 8] = *(const bf16x8*)(Bb + 8);
    }
    __syncthreads();

    s16x8 af[4], bfr[4];
#pragma unroll
    for (int i = 0; i < 4; ++i)
      af[i] = *(const s16x8*)&As[wr * 64 + i * 16 + lrow][kgrp];
#pragma unroll
    for (int j = 0; j < 4; ++j)
      bfr[j] = *(const s16x8*)&Bs[wc * 64 + j * 16 + lrow][kgrp];
#pragma unroll
    for (int i = 0; i < 4; ++i)
#pragma unroll
      for (int j = 0; j < 4; ++j)
        acc[i][j] = __builtin_amdgcn_mfma_f32_16x16x32_bf16(af[i], bfr[j], acc[i][j], 0, 0, 0);
    __syncthreads();
  }

  // epilogue: C/D layout col=lane&15, row=(lane>>4)*4+reg  [m89/m91-verified]
  float bv[4]; int bcol[4];
#pragma unroll
  for (int j = 0; j < 4; ++j) {
    bcol[j] = col0 + wc * 64 + j * 16 + lrow;
    bv[j] = (bcol[j] < N) ? bias[bcol[j]] : 0.f;
  }
  const int rbase = row0 + wr * 64 + (ln >> 4) * 4;
#pragma unroll
  for (int i = 0; i < 4; ++i) {
#pragma unroll
    for (int rr = 0; rr < 4; ++rr) {
      int r = rbase + i * 16 + rr;
      if (r < M) {
#pragma unroll
        for (int j = 0; j < 4; ++j) {
          if (bcol[j] < N) {
            float v = acc[i][j][rr] + bv[j];
            if (ACT == 1) v = (v >= 0.f) ? v : 0.01f * v;
            if (OSEL == 0) ((float*)Cc)[(size_t)r * N + bcol[j]] = v;
            else ((__bf16*)Cc)[(size_t)r * N + bcol[j]] = (__bf16)v;
          }
        }
      }
    }
  }
}

// ---- z_label[b][:] = zE[labels[b]][:] (f32) ----
__global__ __launch_bounds__(256) void gather512_k(const float* __restrict__ zE,
                                                   const int* __restrict__ labels,
                                                   float* __restrict__ dst) {
  int b = blockIdx.x * 4 + (threadIdx.x >> 6);
  int ln = threadIdx.x & 63;
  int g = labels[b]; g = g < 0 ? 0 : (g > 31 ? 31 : g);
#pragma unroll
  for (int q = 0; q < 8; ++q)
    dst[(size_t)b * 512 + ln * 8 + q] = zE[(size_t)g * 512 + ln * 8 + q];
}

// ---- partitionable threefry (verified): bits[i] = o0^o1, counter (0,i) ----
__global__ __launch_bounds__(256) void threefry_s_k(const int* __restrict__ labels,
                                                    float* __restrict__ s) {
  int i = blockIdx.x * blockDim.x + threadIdx.x;
  if (i >= Bn) return;
  unsigned x0 = 0u, x1 = (unsigned)i;
  tf2x32(0u, 1234u, x0, x1);
  unsigned bits = x0 ^ x1;
  float u = __uint_as_float((bits >> 9) | 0x3f800000u) - 1.0f;
  u = fmaxf(u, 0.0f);
  s[i] = (float)labels[i] + u;
}

// ---- ranks via LDS-staged comparisons (global, stable) ----
__global__ __launch_bounds__(256) void rank_k(const int* __restrict__ labels,
                                              const float* __restrict__ s,
                                              int* __restrict__ order,
                                              int* __restrict__ perm) {
  __shared__ unsigned char Ls[8192];
  __shared__ float Ss[8192];
  for (int j = threadIdx.x; j < 8192; j += 256) {
    Ls[j] = (unsigned char)labels[j];
    Ss[j] = s[j];
  }
  __syncthreads();
  int i = blockIdx.x * 256 + threadIdx.x;
  int li = Ls[i];
  float si = Ss[i];
  int ro = 0, rp = 0;
  for (int j = 0; j < Bn; ++j) {
    int lj = Ls[j];
    float sj = Ss[j];
    ro += (lj < li || (lj == li && j < i)) ? 1 : 0;
    rp += (sj < si || (sj == si && j < i)) ? 1 : 0;
  }
  order[ro] = i;
  perm[rp] = i;
}

// ---- per-sample cost*T (IPOT) and softplus(1.5*(cos_neg-cos_pos)) ----
__global__ __launch_bounds__(256) void persample_k(const float* __restrict__ out,
                                                   float* __restrict__ costT,
                                                   float* __restrict__ psamp) {
  int b = blockIdx.x * 4 + (threadIdx.x >> 6);
  int ln = threadIdx.x & 63;
  float dlr = 0.f, dli = 0.f, nl = 0.f, nr = 0.f, ni = 0.f;
#pragma unroll
  for (int q = 0; q < 8; ++q) {
    size_t idx = (size_t)b * 512 + ln * 8 + q;
    float fl = out[ZL_OFF + idx];
    float fr = out[ZR_OFF + idx];
    float fi = out[ZI_OFF + idx];
    dlr += fl * fr; dli += fl * fi;
    nl += fl * fl;  nr += fr * fr;  ni += fi * fi;
  }
#pragma unroll
  for (int off = 32; off; off >>= 1) {
    dlr += __shfl_down(dlr, off);
    dli += __shfl_down(dli, off);
    nl  += __shfl_down(nl,  off);
    nr  += __shfl_down(nr,  off);
    ni  += __shfl_down(ni,  off);
  }
  if (ln == 0) {
    float snl = sqrtf(nl), snr = sqrtf(nr), sni = sqrtf(ni);
    float cost = 1.0f - dlr / (fmaxf(snl, 1e-5f) * fmaxf(snr, 1e-5f));
    float cp = dlr / (fmaxf(snl, 1e-8f) * fmaxf(snr, 1e-8f));
    float cn = dli / (fmaxf(snl, 1e-8f) * fmaxf(sni, 1e-8f));
    float d = 1.5f * (cn - cp);
    float ps = (d > 0.f) ? d + log1pf(expf(-d)) : log1pf(expf(d));
    float a = expf(-cost * 2.0f), sg = 1.f, T = 1.f;
    for (int t = 0; t < 50; ++t) {
      float q = a * T;
      float dl = 1.f / (q * sg);
      sg = 1.f / (dl * q);
      T = dl * q * sg;
    }
    costT[b] = cost * T;
    psamp[b] = ps;
  }
}

__global__ __launch_bounds__(256) void ot_reduce_k(const float* __restrict__ costT,
                                                   float* __restrict__ out) {
  __shared__ float red[256];
  float sum = 0.f;
  for (int i = threadIdx.x; i < Bn; i += 256) sum += costT[i];
  red[threadIdx.x] = sum;
  __syncthreads();
  for (int st = 128; st; st >>= 1) {
    if (threadIdx.x < st) red[threadIdx.x] += red[threadIdx.x + st];
    __syncthreads();
  }
  if (threadIdx.x == 0) out[OT_OFF] = red[0] / (float)Bn;
}

__global__ __launch_bounds__(256) void group_reduce_k(const int* __restrict__ labels,
                                                      const float* __restrict__ psamp,
                                                      float* __restrict__ gmean,
                                                      float* __restrict__ present) {
  int g = blockIdx.x;
  __shared__ float rs[256];
  __shared__ int rc[256];
  float s = 0.f; int c = 0;
  for (int i = threadIdx.x; i < Bn; i += 256)
    if (labels[i] == g) { s += psamp[i]; c++; }
  rs[threadIdx.x] = s; rc[threadIdx.x] = c;
  __syncthreads();
  for (int st = 128; st; st >>= 1) {
    if (threadIdx.x < st) { rs[threadIdx.x] += rs[threadIdx.x + st]; rc[threadIdx.x] += rc[threadIdx.x + st]; }
    __syncthreads();
  }
  if (threadIdx.x == 0) {
    gmean[g] = rc[0] > 0 ? rs[0] / (float)rc[0] : 0.f;
    present[g] = rc[0] > 0 ? 1.f : 0.f;
  }
}

__global__ void contra_final_k(const float* __restrict__ gmean,
                               const float* __restrict__ present,
                               float* __restrict__ out) {
  if (threadIdx.x == 0) {
    float s = 0.f, p = 0.f;
    for (int g = 0; g < 32; ++g) { s += gmean[g]; p += present[g]; }
    out[CT_OFF] = s / p;
  }
}

// ---- x_ori[j] = x[order[j]] (runs LAST; overwrites scratch zone) ----
__global__ __launch_bounds__(128) void xori_k(const float* __restrict__ x,
                                              const int* __restrict__ order,
                                              float* __restrict__ out) {
  int j = blockIdx.x, t = threadIdx.x;
  int o = order[j]; o = o < 0 ? 0 : (o > Bn - 1 ? Bn - 1 : o);
#pragma unroll
  for (int q = 0; q < 8; ++q)
    out[XO_OFF + (size_t)j * 1024 + t * 8 + q] = x[(size_t)o * 1024 + t * 8 + q];
}

// ---- BN partial sums over one 2048-row bf16 chunk ----
__global__ __launch_bounds__(256) void bnacc_k(const __bf16* __restrict__ h,
                                               float* __restrict__ sum,
                                               float* __restrict__ sum2) {
  int colbase = blockIdx.x * 64;
  int lc = threadIdx.x & 63, rg = threadIdx.x >> 6;
  float s = 0.f, s2 = 0.f;
  for (int r = rg; r < 2048; r += 4) {
    float v = (float)h[(size_t)r * 2048 + colbase + lc];
    s += v; s2 += v * v;
  }
  __shared__ float sh[4][64], sh2[4][64];
  sh[rg][lc] = s; sh2[rg][lc] = s2;
  __syncthreads();
  if (rg == 0) {
    s  = sh[0][lc] + sh[1][lc] + sh[2][lc] + sh[3][lc];
    s2 = sh2[0][lc] + sh2[1][lc] + sh2[2][lc] + sh2[3][lc];
    sum[colbase + lc]  = s;
    sum2[colbase + lc] = s2;
  }
}

__global__ __launch_bounds__(256) void bnfinal_k(const float* __restrict__ sumA,
                                                 const float* __restrict__ sum2A,
                                                 const float* __restrict__ gamma,
                                                 const float* __restrict__ beta,
                                                 float* __restrict__ scale,
                                                 float* __restrict__ shift) {
  int c = blockIdx.x * 256 + threadIdx.x;   // 8 blocks -> 2048 cols
  float s = 0.f, s2 = 0.f;
  for (int q = 0; q < 4; ++q) { s += sumA[q * 2048 + c]; s2 += sum2A[q * 2048 + c]; }
  float mu = s / (float)Bn;
  float var = s2 / (float)Bn - mu * mu;
  float sc = gamma[c] / sqrtf(var + 1e-5f);
  scale[c] = sc;
  shift[c] = beta[c] - mu * sc;
}

// ---- BN apply + leaky, in place on one 2048x2048 bf16 chunk ----
__global__ __launch_bounds__(256) void bnapply_k(__bf16* __restrict__ h,
                                                 const float* __restrict__ scale,
                                                 const float* __restrict__ shift) {
  size_t i = (size_t)blockIdx.x * 256 + threadIdx.x;   // x8 over 4,194,304 elems
#pragma unroll
  for (int q = 0; q < 8; ++q) {
    size_t e = i * 8 + q;
    int col = (int)(e & 2047);
    float f = (float)h[e] * scale[col] + shift[col];
    f = (f >= 0.f) ? f : 0.01f * f;
    h[e] = (__bf16)f;
  }
}

__global__ void marker_k(float* __restrict__ p, float v) {
  if (threadIdx.x == 0) *p = v;
}

// ==================================================================================
extern "C" void kernel_launch(void* const* d_in, const int* in_sizes, int n_in,
                              void* d_out, int out_size, void* d_ws, size_t ws_size,
                              hipStream_t stream) {
  const float* x    = (const float*)d_in[0];
  const int*  labels = (const int*)d_in[1];
  const float* Wr1 = (const float*)d_in[2];  const float* br1 = (const float*)d_in[3];
  const float* Wr2 = (const float*)d_in[4];  const float* br2 = (const float*)d_in[5];
  const float* Wi1 = (const float*)d_in[6];  const float* bi1 = (const float*)d_in[7];
  const float* Wi2 = (const float*)d_in[8];  const float* bi2 = (const float*)d_in[9];
  const float* E   = (const float*)d_in[10];
  const float* Wd1 = (const float*)d_in[11]; const float* bd1 = (const float*)d_in[12];
  const float* Wd2 = (const float*)d_in[13]; const float* bd2 = (const float*)d_in[14];
  const float* Wc1 = (const float*)d_in[15]; const float* bc1 = (const float*)d_in[16];
  const float* bng = (const float*)d_in[17]; const float* bnb = (const float*)d_in[18];
  const float* Wc2 = (const float*)d_in[19]; const float* bc2 = (const float*)d_in[20];

  float* out = (float*)d_out;
  dim3 b256(256);
  const int* ni = nullptr;
  const float* nf = nullptr;

  if (ws_size < (1u << 20)) {
    marker_k<<<dim3(1), dim3(64), 0, stream>>>(out + XR_OFF, 110.f);
    return;
  }

  // ---- ws aux ----
  char* wsb = (char*)d_ws;
  float* sval   = (float*)(wsb);            // 32 KB
  float* costT  = (float*)(wsb + 32768);
  float* psamp  = (float*)(wsb + 65536);
  int*   ordr   = (int*)  (wsb + 98304);
  int*   prm    = (int*)  (wsb + 131072);
  float* gmean  = (float*)(wsb + 164096);
  float* present= (float*)(wsb + 164224);
  float* bnscale= (float*)(wsb + 164352);   // 8 KB
  float* bnshift= (float*)(wsb + 172544);   // 8 KB
  float* bnsum  = (float*)(wsb + 180736);   // 4 chunk slots x 2048 = 32 KB
  float* bnsum2 = (float*)(wsb + 213504);   // 32 KB
  __bf16* hE    = (__bf16*)(wsb + 246272);  // 32x2048 bf16 = 128 KB
  float*  zE    = (float*)(wsb + 377344);   // 32x512 f32 = 64 KB

  // ---- scratch inside f32 x_ori region [SB_OFF, SB_OFF+8388607) ----
  __bf16* TA   = (__bf16*)(out + SB_OFF);             // up to 2048x1024 bf16 (1M f32 slots)
  __bf16* TB   = (__bf16*)(out + SB_OFF + 1048576);   // up to 1024x2048 bf16 (1M slots)
  __bf16* hbuf = (__bf16*)(out + SB_OFF + 2097152);   // 2048x2048 bf16 (2M slots)

  // ---- encoder_r (4 chunks of 2048 rows) ----
  transpose_k<<<dim3(64, 32), b256, 0, stream>>>(Wr1, TA, 1024, 2048);   // [2048][1024]
  transpose_k<<<dim3(16, 64), b256, 0, stream>>>(Wr2, TB, 2048, 512);    // [512][2048]
  for (int mc = 0; mc < 4; ++mc) {
    mgemm_k<1,1,1><<<dim3(16, 16), b256, 0, stream>>>(x, (size_t)mc * 2097152, TA, br1,
                                                      hbuf, 2048, 2048, 1024, ni, ni, nf, nf);
    mgemm_k<0,0,0><<<dim3(4, 16), b256, 0, stream>>>(hbuf, 0, TB, br2,
                                                     out + ZR_OFF + (size_t)mc * 1048576,
                                                     2048, 512, 2048, ni, ni, nf, nf);
  }
  // ---- label encoder + gather ----
  mgemm_k<1,1,1><<<dim3(16, 1), b256, 0, stream>>>(E, 0, TA, br1, hE, 32, 2048, 1024,
                                                   ni, ni, nf, nf);
  mgemm_k<0,0,0><<<dim3(4, 1), b256, 0, stream>>>(hE, 0, TB, br2, zE, 32, 512, 2048,
                                                  ni, ni, nf, nf);
  gather512_k<<<dim3(2048), b256, 0, stream>>>(zE, labels, out + ZL_OFF);

  // ---- encoder_i ----
  transpose_k<<<dim3(64, 32), b256, 0, stream>>>(Wi1, TA, 1024, 2048);
  transpose_k<<<dim3(16, 64), b256, 0, stream>>>(Wi2, TB, 2048, 512);
  for (int mc = 0; mc < 4; ++mc) {
    mgemm_k<1,1,1><<<dim3(16, 16), b256, 0, stream>>>(x, (size_t)mc * 2097152, TA, bi1,
                                                      hbuf, 2048, 2048, 1024, ni, ni, nf, nf);
    mgemm_k<0,0,0><<<dim3(4, 16), b256, 0, stream>>>(hbuf, 0, TB, bi2,
                                                     out + ZI_OFF + (size_t)mc * 1048576,
                                                     2048, 512, 2048, ni, ni, nf, nf);
  }

  // ---- permutations + per-sample losses ----
  threefry_s_k<<<dim3(32), b256, 0, stream>>>(labels, sval);
  rank_k<<<dim3(32), b256, 0, stream>>>(labels, sval, ordr, prm);
  persample_k<<<dim3(2048), b256, 0, stream>>>(out, costT, psamp);
  group_reduce_k<<<dim3(32), b256, 0, stream>>>(labels, psamp, gmean, present);

  // ---- decoder (gather fused into L1 A-staging) ----
  transpose_k<<<dim3(64, 32), b256, 0, stream>>>(Wd1, TA, 1024, 2048);   // [2048][1024]
  transpose_k<<<dim3(32, 64), b256, 0, stream>>>(Wd2, TB, 2048, 1024);   // [1024][2048]
  for (int mc = 0; mc < 4; ++mc) {
    mgemm_k<1,2,1><<<dim3(16, 16), b256, 0, stream>>>(
        nf, 0, TA, bd1, hbuf, 2048, 2048, 1024,
        prm + mc * 2048, ordr + mc * 2048, out + ZR_OFF, out + ZI_OFF);
    mgemm_k<0,0,0><<<dim3(8, 16), b256, 0, stream>>>(hbuf, 0, TB, bd2,
                                                     out + XR_OFF + (size_t)mc * 2097152,
                                                     2048, 1024, 2048, ni, ni, nf, nf);
  }

  // ---- classifier (two passes over 2048-row chunks; h recomputed) ----
  transpose_k<<<dim3(64, 16), b256, 0, stream>>>(Wc1, TA, 512, 2048);    // [2048][512]
  transpose_k<<<dim3(1, 64), b256, 0, stream>>>(Wc2, TB, 2048, 32);      // [32][2048]
  for (int mc = 0; mc < 4; ++mc) {
    mgemm_k<0,1,1><<<dim3(16, 16), b256, 0, stream>>>(out, ZR_OFF + (size_t)mc * 1048576,
                                                      TA, bc1, hbuf, 2048, 2048, 512,
                                                      ni, ni, nf, nf);
    bnacc_k<<<dim3(32), b256, 0, stream>>>(hbuf, bnsum + mc * 2048, bnsum2 + mc * 2048);
  }
  bnfinal_k<<<dim3(8), b256, 0, stream>>>(bnsum, bnsum2, bng, bnb, bnscale, bnshift);
  for (int mc = 0; mc < 4; ++mc) {
    mgemm_k<0,1,1><<<dim3(16, 16), b256, 0, stream>>>(out, ZR_OFF + (size_t)mc * 1048576,
                                                      TA, bc1, hbuf, 2048, 2048, 512,
                                                      ni, ni, nf, nf);
    bnapply_k<<<dim3(2048), b256, 0, stream>>>(hbuf, bnscale, bnshift);
    mgemm_k<0,0,0><<<dim3(1, 16), b256, 0, stream>>>(hbuf, 0, TB, bc2,
                                                     out + LG_OFF + (size_t)mc * 65536,
                                                     2048, 32, 2048, ni, ni, nf, nf);
  }

  // ---- scalar finals, then x_ori gather LAST (kills scratch zone) ----
  ot_reduce_k<<<dim3(1), b256, 0, stream>>>(costT, out);
  contra_final_k<<<dim3(1), dim3(64), 0, stream>>>(gmean, present, out);
  xori_k<<<dim3(8192), dim3(128), 0, stream>>>(x, ordr, out);

  (void)in_sizes; (void)n_in; (void)out_size;
}

// Round 18
// 2559.959 us; speedup vs baseline: 3.8238x; 1.1378x over previous
//
#include <hip/hip_runtime.h>

typedef short  s16x8 __attribute__((ext_vector_type(8)));
typedef __bf16 bf16x8 __attribute__((ext_vector_type(8)));
typedef float  f32x4 __attribute__((ext_vector_type(4)));

static constexpr int Bn = 8192;
static constexpr size_t XR_OFF = 0;
static constexpr size_t ZL_OFF = 8388608;
static constexpr size_t ZR_OFF = 12582912;
static constexpr size_t ZI_OFF = 16777216;
static constexpr size_t OT_OFF = 20971520;
static constexpr size_t XO_OFF = 20971521;
static constexpr size_t CT_OFF = 29360129;
static constexpr size_t LG_OFF = 29360130;
static constexpr size_t SB_OFF = 20971522;

__device__ __forceinline__ void gload_lds16(const void* g, void* l) {
  __builtin_amdgcn_global_load_lds((const __attribute__((address_space(1))) void*)g,
                                   (__attribute__((address_space(3))) void*)l, 16, 0, 0);
}

__device__ __forceinline__ void tf2x32(unsigned k0, unsigned k1, unsigned& x0, unsigned& x1) {
  const unsigned ks[3] = {k0, k1, k0 ^ k1 ^ 0x1BD11BDAu};
  x0 += ks[0]; x1 += ks[1];
  const int R1r[4] = {13, 15, 26, 6}, R2r[4] = {17, 29, 16, 24};
#pragma unroll
  for (int g = 0; g < 5; ++g) {
    const int* rr = (g & 1) ? R2r : R1r;
#pragma unroll
    for (int q = 0; q < 4; ++q) {
      x0 += x1;
      x1 = (x1 << rr[q]) | (x1 >> (32 - rr[q]));
      x1 ^= x0;
    }
    x0 += ks[(g + 1) % 3];
    x1 += ks[(g + 2) % 3] + (unsigned)(g + 1);
  }
}

__global__ __launch_bounds__(256) void transpose_k(const float* __restrict__ in,
                                                   __bf16* __restrict__ out,
                                                   int R, int C) {
  __shared__ float t[32][33];
  int c0 = blockIdx.x * 32, r0 = blockIdx.y * 32;
  int lc = threadIdx.x & 31, lr = threadIdx.x >> 5;
#pragma unroll
  for (int i = 0; i < 4; ++i) {
    int r = lr + i * 8;
    t[r][lc] = in[(size_t)(r0 + r) * C + c0 + lc];
  }
  __syncthreads();
#pragma unroll
  for (int i = 0; i < 4; ++i) {
    int cc = lr + i * 8;
    out[(size_t)(c0 + cc) * R + r0 + lc] = (__bf16)t[lc][cc];
  }
}

__global__ __launch_bounds__(256) void cvt_k(const float* __restrict__ in,
                                             __bf16* __restrict__ out) {
  size_t i = ((size_t)blockIdx.x * 256 + threadIdx.x) * 8;
  f32x4 v0 = *(const f32x4*)(in + i);
  f32x4 v1 = *(const f32x4*)(in + i + 4);
  bf16x8 o;
#pragma unroll
  for (int q = 0; q < 4; ++q) { o[q] = (__bf16)v0[q]; o[q + 4] = (__bf16)v1[q]; }
  *(bf16x8*)(out + i) = o;
}

// ---- MFMA GEMM: C = act(A @ BT^T + bias), 128x128 tile, BK=32 ----
// AMODE: 0 = A bf16 (global_load_lds); 1 = A f32 (reg-cvt); 2 = gather concat(zr[prm],zi[ord])
// OSEL : 0 = C f32; 1 = C bf16
template <int ACT, int AMODE, int OSEL>
__global__ __launch_bounds__(256) void mgemm_k(const void* __restrict__ A, size_t aoff,
                                               const __bf16* __restrict__ BT,
                                               const float* __restrict__ bias,
                                               void* __restrict__ Cc,
                                               int M, int N, int K,
                                               const int* __restrict__ prmq,
                                               const int* __restrict__ ordq,
                                               const float* __restrict__ zr,
                                               const float* __restrict__ zi) {
  __shared__ __bf16 As[128][32];
  __shared__ __bf16 Bs[128][32];
  const int tid = threadIdx.x;
  const int wv = tid >> 6, ln = tid & 63;
  const int row0 = blockIdx.y * 128, col0 = blockIdx.x * 128;
  const int wr = wv >> 1, wc = wv & 1;
  const int lrow = ln & 15;
  const int kgrp = (ln >> 4) * 8;
  const int srow = tid >> 1;
  const int skh  = (tid & 1) * 16;

  f32x4 acc[4][4] = {};

  int sga = row0 + srow; sga = sga < M ? sga : M - 1;
  int pidx = 0, oidx = 0;
  if (AMODE == 2) {
    pidx = prmq[sga]; pidx = pidx < 0 ? 0 : (pidx > Bn - 1 ? Bn - 1 : pidx);
    oidx = ordq[sga]; oidx = oidx < 0 ? 0 : (oidx > Bn - 1 ? Bn - 1 : oidx);
  }

  for (int k0 = 0; k0 < K; k0 += 32) {
#pragma unroll
    for (int it = 0; it < 2; ++it) {
      int byteoff = it * 4096 + wv * 1024 + ln * 16;
      int r = byteoff >> 6;
      int k8 = (byteoff >> 4) & 3;
      int gb = col0 + r; gb = gb < N ? gb : N - 1;
      gload_lds16(BT + (size_t)gb * K + k0 + k8 * 8, &Bs[0][0] + it * 2048 + wv * 512);
    }
    if (AMODE == 0) {
#pragma unroll
      for (int it = 0; it < 2; ++it) {
        int byteoff = it * 4096 + wv * 1024 + ln * 16;
        int r = byteoff >> 6;
        int k8 = (byteoff >> 4) & 3;
        int gr = row0 + r; gr = gr < M ? gr : M - 1;
        gload_lds16((const __bf16*)A + aoff + (size_t)gr * K + k0 + k8 * 8,
                    &As[0][0] + it * 2048 + wv * 512);
      }
    } else {
      const int kk = k0 + skh;
      const float* Af;
      if (AMODE == 1) Af = (const float*)A + aoff + (size_t)sga * K + kk;
      else Af = (kk < 512) ? (zr + (size_t)pidx * 512 + kk)
                           : (zi + (size_t)oidx * 512 + (kk - 512));
      f32x4 v0 = *(const f32x4*)(Af + 0);
      f32x4 v1 = *(const f32x4*)(Af + 4);
      f32x4 v2 = *(const f32x4*)(Af + 8);
      f32x4 v3 = *(const f32x4*)(Af + 12);
      bf16x8 alo, ahi;
#pragma unroll
      for (int q = 0; q < 4; ++q) { alo[q] = (__bf16)v0[q]; alo[q + 4] = (__bf16)v1[q]; }
#pragma unroll
      for (int q = 0; q < 4; ++q) { ahi[q] = (__bf16)v2[q]; ahi[q + 4] = (__bf16)v3[q]; }
      *(bf16x8*)&As[srow][skh]     = alo;
      *(bf16x8*)&As[srow][skh + 8] = ahi;
    }
    __syncthreads();

    s16x8 af[4], bfr[4];
#pragma unroll
    for (int i = 0; i < 4; ++i)
      af[i] = *(const s16x8*)&As[wr * 64 + i * 16 + lrow][kgrp];
#pragma unroll
    for (int j = 0; j < 4; ++j)
      bfr[j] = *(const s16x8*)&Bs[wc * 64 + j * 16 + lrow][kgrp];
#pragma unroll
    for (int i = 0; i < 4; ++i)
#pragma unroll
      for (int j = 0; j < 4; ++j)
        acc[i][j] = __builtin_amdgcn_mfma_f32_16x16x32_bf16(af[i], bfr[j], acc[i][j], 0, 0, 0);
    __syncthreads();
  }

  float bv[4]; int bcol[4];
#pragma unroll
  for (int j = 0; j < 4; ++j) {
    bcol[j] = col0 + wc * 64 + j * 16 + lrow;
    bv[j] = (bcol[j] < N) ? bias[bcol[j]] : 0.f;
  }
  const int rbase = row0 + wr * 64 + (ln >> 4) * 4;
#pragma unroll
  for (int i = 0; i < 4; ++i) {
#pragma unroll
    for (int rr = 0; rr < 4; ++rr) {
      int r = rbase + i * 16 + rr;
      if (r < M) {
#pragma unroll
        for (int j = 0; j < 4; ++j) {
          if (bcol[j] < N) {
            float v = acc[i][j][rr] + bv[j];
            if (ACT == 1) v = (v >= 0.f) ? v : 0.01f * v;
            if (OSEL == 0) ((float*)Cc)[(size_t)r * N + bcol[j]] = v;
            else ((__bf16*)Cc)[(size_t)r * N + bcol[j]] = (__bf16)v;
          }
        }
      }
    }
  }
}

__global__ __launch_bounds__(256) void gather512_k(const float* __restrict__ zE,
                                                   const int* __restrict__ labels,
                                                   float* __restrict__ dst) {
  int b = blockIdx.x * 4 + (threadIdx.x >> 6);
  int ln = threadIdx.x & 63;
  int g = labels[b]; g = g < 0 ? 0 : (g > 31 ? 31 : g);
#pragma unroll
  for (int q = 0; q < 8; ++q)
    dst[(size_t)b * 512 + ln * 8 + q] = zE[(size_t)g * 512 + ln * 8 + q];
}

__global__ __launch_bounds__(256) void threefry_s_k(const int* __restrict__ labels,
                                                    float* __restrict__ s) {
  int i = blockIdx.x * blockDim.x + threadIdx.x;
  if (i >= Bn) return;
  unsigned x0 = 0u, x1 = (unsigned)i;
  tf2x32(0u, 1234u, x0, x1);
  unsigned bits = x0 ^ x1;
  float u = __uint_as_float((bits >> 9) | 0x3f800000u) - 1.0f;
  u = fmaxf(u, 0.0f);
  s[i] = (float)labels[i] + u;
}

// ---- ranks: 256 blocks x (32 i's x 8-lane split) ----
__global__ __launch_bounds__(256) void rank_k(const int* __restrict__ labels,
                                              const float* __restrict__ s,
                                              int* __restrict__ order,
                                              int* __restrict__ perm) {
  __shared__ unsigned char Ls[8192];
  __shared__ float Ss[8192];
  for (int j = threadIdx.x; j < 8192; j += 256) {
    Ls[j] = (unsigned char)labels[j];
    Ss[j] = s[j];
  }
  __syncthreads();
  int i = blockIdx.x * 32 + (threadIdx.x >> 3);
  int part = threadIdx.x & 7;
  int li = Ls[i];
  float si = Ss[i];
  int ro = 0, rp = 0;
  for (int j = part * 1024; j < (part + 1) * 1024; ++j) {
    int lj = Ls[j];
    float sj = Ss[j];
    ro += (lj < li || (lj == li && j < i)) ? 1 : 0;
    rp += (sj < si || (sj == si && j < i)) ? 1 : 0;
  }
#pragma unroll
  for (int d = 4; d; d >>= 1) {
    ro += __shfl_down(ro, d);
    rp += __shfl_down(rp, d);
  }
  if (part == 0) {
    order[ro] = i;
    perm[rp] = i;
  }
}

__global__ __launch_bounds__(256) void persample_k(const float* __restrict__ out,
                                                   float* __restrict__ costT,
                                                   float* __restrict__ psamp) {
  int b = blockIdx.x * 4 + (threadIdx.x >> 6);
  int ln = threadIdx.x & 63;
  float dlr = 0.f, dli = 0.f, nl = 0.f, nr = 0.f, ni = 0.f;
#pragma unroll
  for (int q = 0; q < 8; ++q) {
    size_t idx = (size_t)b * 512 + ln * 8 + q;
    float fl = out[ZL_OFF + idx];
    float fr = out[ZR_OFF + idx];
    float fi = out[ZI_OFF + idx];
    dlr += fl * fr; dli += fl * fi;
    nl += fl * fl;  nr += fr * fr;  ni += fi * fi;
  }
#pragma unroll
  for (int off = 32; off; off >>= 1) {
    dlr += __shfl_down(dlr, off);
    dli += __shfl_down(dli, off);
    nl  += __shfl_down(nl,  off);
    nr  += __shfl_down(nr,  off);
    ni  += __shfl_down(ni,  off);
  }
  if (ln == 0) {
    float snl = sqrtf(nl), snr = sqrtf(nr), sni = sqrtf(ni);
    float cost = 1.0f - dlr / (fmaxf(snl, 1e-5f) * fmaxf(snr, 1e-5f));
    float cp = dlr / (fmaxf(snl, 1e-8f) * fmaxf(snr, 1e-8f));
    float cn = dli / (fmaxf(snl, 1e-8f) * fmaxf(sni, 1e-8f));
    float d = 1.5f * (cn - cp);
    float ps = (d > 0.f) ? d + log1pf(expf(-d)) : log1pf(expf(d));
    float a = expf(-cost * 2.0f), sg = 1.f, T = 1.f;
    for (int t = 0; t < 50; ++t) {
      float q = a * T;
      float dl = 1.f / (q * sg);
      sg = 1.f / (dl * q);
      T = dl * q * sg;
    }
    costT[b] = cost * T;
    psamp[b] = ps;
  }
}

__global__ __launch_bounds__(256) void ot_reduce_k(const float* __restrict__ costT,
                                                   float* __restrict__ out) {
  __shared__ float red[256];
  float sum = 0.f;
  for (int i = threadIdx.x; i < Bn; i += 256) sum += costT[i];
  red[threadIdx.x] = sum;
  __syncthreads();
  for (int st = 128; st; st >>= 1) {
    if (threadIdx.x < st) red[threadIdx.x] += red[threadIdx.x + st];
    __syncthreads();
  }
  if (threadIdx.x == 0) out[OT_OFF] = red[0] / (float)Bn;
}

__global__ __launch_bounds__(256) void group_reduce_k(const int* __restrict__ labels,
                                                      const float* __restrict__ psamp,
                                                      float* __restrict__ gmean,
                                                      float* __restrict__ present) {
  int g = blockIdx.x;
  __shared__ float rs[256];
  __shared__ int rc[256];
  float s = 0.f; int c = 0;
  for (int i = threadIdx.x; i < Bn; i += 256)
    if (labels[i] == g) { s += psamp[i]; c++; }
  rs[threadIdx.x] = s; rc[threadIdx.x] = c;
  __syncthreads();
  for (int st = 128; st; st >>= 1) {
    if (threadIdx.x < st) { rs[threadIdx.x] += rs[threadIdx.x + st]; rc[threadIdx.x] += rc[threadIdx.x + st]; }
    __syncthreads();
  }
  if (threadIdx.x == 0) {
    gmean[g] = rc[0] > 0 ? rs[0] / (float)rc[0] : 0.f;
    present[g] = rc[0] > 0 ? 1.f : 0.f;
  }
}

__global__ void contra_final_k(const float* __restrict__ gmean,
                               const float* __restrict__ present,
                               float* __restrict__ out) {
  if (threadIdx.x == 0) {
    float s = 0.f, p = 0.f;
    for (int g = 0; g < 32; ++g) { s += gmean[g]; p += present[g]; }
    out[CT_OFF] = s / p;
  }
}

__global__ __launch_bounds__(128) void xori_k(const float* __restrict__ x,
                                              const int* __restrict__ order,
                                              float* __restrict__ out) {
  int j = blockIdx.x, t = threadIdx.x;
  int o = order[j]; o = o < 0 ? 0 : (o > Bn - 1 ? Bn - 1 : o);
#pragma unroll
  for (int q = 0; q < 8; ++q)
    out[XO_OFF + (size_t)j * 1024 + t * 8 + q] = x[(size_t)o * 1024 + t * 8 + q];
}

__global__ __launch_bounds__(256) void bnacc_k(const __bf16* __restrict__ h,
                                               float* __restrict__ sum,
                                               float* __restrict__ sum2) {
  int colbase = blockIdx.x * 64;
  int lc = threadIdx.x & 63, rg = threadIdx.x >> 6;
  float s = 0.f, s2 = 0.f;
  for (int r = rg; r < 2048; r += 4) {
    float v = (float)h[(size_t)r * 2048 + colbase + lc];
    s += v; s2 += v * v;
  }
  __shared__ float sh[4][64], sh2[4][64];
  sh[rg][lc] = s; sh2[rg][lc] = s2;
  __syncthreads();
  if (rg == 0) {
    s  = sh[0][lc] + sh[1][lc] + sh[2][lc] + sh[3][lc];
    s2 = sh2[0][lc] + sh2[1][lc] + sh2[2][lc] + sh2[3][lc];
    sum[colbase + lc]  = s;
    sum2[colbase + lc] = s2;
  }
}

__global__ __launch_bounds__(256) void bnfinal_k(const float* __restrict__ sumA,
                                                 const float* __restrict__ sum2A,
                                                 const float* __restrict__ gamma,
                                                 const float* __restrict__ beta,
                                                 float* __restrict__ scale,
                                                 float* __restrict__ shift) {
  int c = blockIdx.x * 256 + threadIdx.x;
  float s = 0.f, s2 = 0.f;
  for (int q = 0; q < 4; ++q) { s += sumA[q * 2048 + c]; s2 += sum2A[q * 2048 + c]; }
  float mu = s / (float)Bn;
  float var = s2 / (float)Bn - mu * mu;
  float sc = gamma[c] / sqrtf(var + 1e-5f);
  scale[c] = sc;
  shift[c] = beta[c] - mu * sc;
}

__global__ __launch_bounds__(256) void bnapply_k(__bf16* __restrict__ h,
                                                 const float* __restrict__ scale,
                                                 const float* __restrict__ shift) {
  size_t i = (size_t)blockIdx.x * 256 + threadIdx.x;
#pragma unroll
  for (int q = 0; q < 8; ++q) {
    size_t e = i * 8 + q;
    int col = (int)(e & 2047);
    float f = (float)h[e] * scale[col] + shift[col];
    f = (f >= 0.f) ? f : 0.01f * f;
    h[e] = (__bf16)f;
  }
}

__global__ void marker_k(float* __restrict__ p, float v) {
  if (threadIdx.x == 0) *p = v;
}

// ==================================================================================
extern "C" void kernel_launch(void* const* d_in, const int* in_sizes, int n_in,
                              void* d_out, int out_size, void* d_ws, size_t ws_size,
                              hipStream_t stream) {
  const float* x    = (const float*)d_in[0];
  const int*  labels = (const int*)d_in[1];
  const float* Wr1 = (const float*)d_in[2];  const float* br1 = (const float*)d_in[3];
  const float* Wr2 = (const float*)d_in[4];  const float* br2 = (const float*)d_in[5];
  const float* Wi1 = (const float*)d_in[6];  const float* bi1 = (const float*)d_in[7];
  const float* Wi2 = (const float*)d_in[8];  const float* bi2 = (const float*)d_in[9];
  const float* E   = (const float*)d_in[10];
  const float* Wd1 = (const float*)d_in[11]; const float* bd1 = (const float*)d_in[12];
  const float* Wd2 = (const float*)d_in[13]; const float* bd2 = (const float*)d_in[14];
  const float* Wc1 = (const float*)d_in[15]; const float* bc1 = (const float*)d_in[16];
  const float* bng = (const float*)d_in[17]; const float* bnb = (const float*)d_in[18];
  const float* Wc2 = (const float*)d_in[19]; const float* bc2 = (const float*)d_in[20];

  float* out = (float*)d_out;
  dim3 b256(256);
  const int* ni = nullptr;
  const float* nf = nullptr;
  void* nv = nullptr;

  if (ws_size < (1u << 20)) {
    marker_k<<<dim3(1), dim3(64), 0, stream>>>(out + XR_OFF, 110.f);
    return;
  }

  char* wsb = (char*)d_ws;
  float* sval   = (float*)(wsb);
  float* costT  = (float*)(wsb + 32768);
  float* psamp  = (float*)(wsb + 65536);
  int*   ordr   = (int*)  (wsb + 98304);
  int*   prm    = (int*)  (wsb + 131072);
  float* gmean  = (float*)(wsb + 164096);
  float* present= (float*)(wsb + 164224);
  float* bnscale= (float*)(wsb + 164352);
  float* bnshift= (float*)(wsb + 172544);
  float* bnsum  = (float*)(wsb + 180736);
  float* bnsum2 = (float*)(wsb + 213504);
  __bf16* hE    = (__bf16*)(wsb + 246272);
  float*  zE    = (float*)(wsb + 377344);

  // Phase E scratch (f32 slots): TAB[0,2M) TB2[2M,3M) hL[3M,5M) hR[5M,7M) xch[7M,8M)
  __bf16* TAB  = (__bf16*)(out + SB_OFF);              // [4096][1024] (Wr1T rows 0-2047, Wi1T 2048-4095)
  __bf16* TB2  = (__bf16*)(out + SB_OFF + 2097152);    // [1024][2048] (Wr2T 0-511, Wi2T 512-1023)
  __bf16* hL   = (__bf16*)(out + SB_OFF + 3145728);    // [2048][2048]
  __bf16* hR   = (__bf16*)(out + SB_OFF + 5242880);    // [2048][2048]
  __bf16* xch  = (__bf16*)(out + SB_OFF + 7340032);    // [2048][1024]
  // Phase D/C scratch
  __bf16* TAd   = (__bf16*)(out + SB_OFF);             // [2048][1024]
  __bf16* TBd   = (__bf16*)(out + SB_OFF + 1048576);   // [1024][2048]
  __bf16* hbufd = (__bf16*)(out + SB_OFF + 2097152);   // [2048][2048]
  __bf16* TAc   = (__bf16*)(out + SB_OFF);             // [2048][512]
  __bf16* TBc   = (__bf16*)(out + SB_OFF + 524288);    // [32][2048]

  // ---- merged encoders ----
  transpose_k<<<dim3(64, 32), b256, 0, stream>>>(Wr1, TAB, 1024, 2048);
  transpose_k<<<dim3(64, 32), b256, 0, stream>>>(Wi1, TAB + 2097152, 1024, 2048);
  transpose_k<<<dim3(16, 64), b256, 0, stream>>>(Wr2, TB2, 2048, 512);
  transpose_k<<<dim3(16, 64), b256, 0, stream>>>(Wi2, TB2 + 1048576, 2048, 512);
  for (int mc = 0; mc < 4; ++mc) {
    cvt_k<<<dim3(1024), b256, 0, stream>>>(x + (size_t)mc * 2097152, xch);
    mgemm_k<1,0,1><<<dim3(16, 16), b256, 0, stream>>>(xch, 0, TAB, br1, hL,
                                                      2048, 2048, 1024, ni, ni, nf, nf);
    mgemm_k<1,0,1><<<dim3(16, 16), b256, 0, stream>>>(xch, 0, TAB + 2097152, bi1, hR,
                                                      2048, 2048, 1024, ni, ni, nf, nf);
    mgemm_k<0,0,0><<<dim3(4, 16), b256, 0, stream>>>(hL, 0, TB2, br2,
                                                     out + ZR_OFF + (size_t)mc * 1048576,
                                                     2048, 512, 2048, ni, ni, nf, nf);
    mgemm_k<0,0,0><<<dim3(4, 16), b256, 0, stream>>>(hR, 0, TB2 + 1048576, bi2,
                                                     out + ZI_OFF + (size_t)mc * 1048576,
                                                     2048, 512, 2048, ni, ni, nf, nf);
  }
  // ---- label encoder + gather ----
  mgemm_k<1,1,1><<<dim3(16, 1), b256, 0, stream>>>(E, 0, TAB, br1, hE,
                                                   32, 2048, 1024, ni, ni, nf, nf);
  mgemm_k<0,0,0><<<dim3(4, 1), b256, 0, stream>>>(hE, 0, TB2, br2, zE,
                                                  32, 512, 2048, ni, ni, nf, nf);
  gather512_k<<<dim3(2048), b256, 0, stream>>>(zE, labels, out + ZL_OFF);

  // ---- permutations + per-sample losses ----
  threefry_s_k<<<dim3(32), b256, 0, stream>>>(labels, sval);
  rank_k<<<dim3(256), b256, 0, stream>>>(labels, sval, ordr, prm);
  persample_k<<<dim3(2048), b256, 0, stream>>>(out, costT, psamp);
  group_reduce_k<<<dim3(32), b256, 0, stream>>>(labels, psamp, gmean, present);

  // ---- decoder ----
  transpose_k<<<dim3(64, 32), b256, 0, stream>>>(Wd1, TAd, 1024, 2048);
  transpose_k<<<dim3(32, 64), b256, 0, stream>>>(Wd2, TBd, 2048, 1024);
  for (int mc = 0; mc < 4; ++mc) {
    mgemm_k<1,2,1><<<dim3(16, 16), b256, 0, stream>>>(
        nv, 0, TAd, bd1, hbufd, 2048, 2048, 1024,
        prm + mc * 2048, ordr + mc * 2048, out + ZR_OFF, out + ZI_OFF);
    mgemm_k<0,0,0><<<dim3(8, 16), b256, 0, stream>>>(hbufd, 0, TBd, bd2,
                                                     out + XR_OFF + (size_t)mc * 2097152,
                                                     2048, 1024, 2048, ni, ni, nf, nf);
  }

  // ---- classifier ----
  transpose_k<<<dim3(64, 16), b256, 0, stream>>>(Wc1, TAc, 512, 2048);
  transpose_k<<<dim3(1, 64), b256, 0, stream>>>(Wc2, TBc, 2048, 32);
  for (int mc = 0; mc < 4; ++mc) {
    mgemm_k<0,1,1><<<dim3(16, 16), b256, 0, stream>>>(out, ZR_OFF + (size_t)mc * 1048576,
                                                      TAc, bc1, hbufd,
                                                      2048, 2048, 512, ni, ni, nf, nf);
    bnacc_k<<<dim3(32), b256, 0, stream>>>(hbufd, bnsum + mc * 2048, bnsum2 + mc * 2048);
  }
  bnfinal_k<<<dim3(8), b256, 0, stream>>>(bnsum, bnsum2, bng, bnb, bnscale, bnshift);
  for (int mc = 0; mc < 4; ++mc) {
    mgemm_k<0,1,1><<<dim3(16, 16), b256, 0, stream>>>(out, ZR_OFF + (size_t)mc * 1048576,
                                                      TAc, bc1, hbufd,
                                                      2048, 2048, 512, ni, ni, nf, nf);
    bnapply_k<<<dim3(2048), b256, 0, stream>>>(hbufd, bnscale, bnshift);
    mgemm_k<0,0,0><<<dim3(1, 16), b256, 0, stream>>>(hbufd, 0, TBc, bc2,
                                                     out + LG_OFF + (size_t)mc * 65536,
                                                     2048, 32, 2048, ni, ni, nf, nf);
  }

  // ---- scalar finals, x_ori LAST ----
  ot_reduce_k<<<dim3(1), b256, 0, stream>>>(costT, out);
  contra_final_k<<<dim3(1), dim3(64), 0, stream>>>(gmean, present, out);
  xori_k<<<dim3(8192), dim3(128), 0, stream>>>(x, ordr, out);

  (void)in_sizes; (void)n_in; (void)out_size;
}

// Round 19
// 2006.559 us; speedup vs baseline: 4.8784x; 1.2758x over previous
//
#include <hip/hip_runtime.h>

typedef short  s16x8 __attribute__((ext_vector_type(8)));
typedef __bf16 bf16x8 __attribute__((ext_vector_type(8)));
typedef float  f32x4 __attribute__((ext_vector_type(4)));

static constexpr int Bn = 8192;
static constexpr size_t XR_OFF = 0;
static constexpr size_t ZL_OFF = 8388608;
static constexpr size_t ZR_OFF = 12582912;
static constexpr size_t ZI_OFF = 16777216;
static constexpr size_t OT_OFF = 20971520;
static constexpr size_t XO_OFF = 20971521;
static constexpr size_t CT_OFF = 29360129;
static constexpr size_t LG_OFF = 29360130;
static constexpr size_t SB_OFF = 20971522;

__device__ __forceinline__ void gload_lds16(const void* g, void* l) {
  __builtin_amdgcn_global_load_lds((const __attribute__((address_space(1))) void*)g,
                                   (__attribute__((address_space(3))) void*)l, 16, 0, 0);
}

__device__ __forceinline__ void tf2x32(unsigned k0, unsigned k1, unsigned& x0, unsigned& x1) {
  const unsigned ks[3] = {k0, k1, k0 ^ k1 ^ 0x1BD11BDAu};
  x0 += ks[0]; x1 += ks[1];
  const int R1r[4] = {13, 15, 26, 6}, R2r[4] = {17, 29, 16, 24};
#pragma unroll
  for (int g = 0; g < 5; ++g) {
    const int* rr = (g & 1) ? R2r : R1r;
#pragma unroll
    for (int q = 0; q < 4; ++q) {
      x0 += x1;
      x1 = (x1 << rr[q]) | (x1 >> (32 - rr[q]));
      x1 ^= x0;
    }
    x0 += ks[(g + 1) % 3];
    x1 += ks[(g + 2) % 3] + (unsigned)(g + 1);
  }
}

__global__ __launch_bounds__(256) void transpose_k(const float* __restrict__ in,
                                                   __bf16* __restrict__ out,
                                                   int R, int C) {
  __shared__ float t[32][33];
  int c0 = blockIdx.x * 32, r0 = blockIdx.y * 32;
  int lc = threadIdx.x & 31, lr = threadIdx.x >> 5;
#pragma unroll
  for (int i = 0; i < 4; ++i) {
    int r = lr + i * 8;
    t[r][lc] = in[(size_t)(r0 + r) * C + c0 + lc];
  }
  __syncthreads();
#pragma unroll
  for (int i = 0; i < 4; ++i) {
    int cc = lr + i * 8;
    out[(size_t)(c0 + cc) * R + r0 + lc] = (__bf16)t[lc][cc];
  }
}

__global__ __launch_bounds__(256) void cvt_k(const float* __restrict__ in,
                                             __bf16* __restrict__ out) {
  size_t i = ((size_t)blockIdx.x * 256 + threadIdx.x) * 8;
  f32x4 v0 = *(const f32x4*)(in + i);
  f32x4 v1 = *(const f32x4*)(in + i + 4);
  bf16x8 o;
#pragma unroll
  for (int q = 0; q < 4; ++q) { o[q] = (__bf16)v0[q]; o[q + 4] = (__bf16)v1[q]; }
  *(bf16x8*)(out + i) = o;
}

// ---- MFMA GEMM: C = act(A @ BT^T + bias), 128x128 tile, BK=32 ----
template <int ACT, int AMODE, int OSEL>
__global__ __launch_bounds__(256) void mgemm_k(const void* __restrict__ A, size_t aoff,
                                               const __bf16* __restrict__ BT,
                                               const float* __restrict__ bias,
                                               void* __restrict__ Cc,
                                               int M, int N, int K,
                                               const int* __restrict__ prmq,
                                               const int* __restrict__ ordq,
                                               const float* __restrict__ zr,
                                               const float* __restrict__ zi) {
  __shared__ __bf16 As[128][32];
  __shared__ __bf16 Bs[128][32];
  const int tid = threadIdx.x;
  const int wv = tid >> 6, ln = tid & 63;
  const int row0 = blockIdx.y * 128, col0 = blockIdx.x * 128;
  const int wr = wv >> 1, wc = wv & 1;
  const int lrow = ln & 15;
  const int kgrp = (ln >> 4) * 8;
  const int srow = tid >> 1;
  const int skh  = (tid & 1) * 16;

  f32x4 acc[4][4] = {};

  int sga = row0 + srow; sga = sga < M ? sga : M - 1;
  int pidx = 0, oidx = 0;
  if (AMODE == 2) {
    pidx = prmq[sga]; pidx = pidx < 0 ? 0 : (pidx > Bn - 1 ? Bn - 1 : pidx);
    oidx = ordq[sga]; oidx = oidx < 0 ? 0 : (oidx > Bn - 1 ? Bn - 1 : oidx);
  }

  for (int k0 = 0; k0 < K; k0 += 32) {
#pragma unroll
    for (int it = 0; it < 2; ++it) {
      int byteoff = it * 4096 + wv * 1024 + ln * 16;
      int r = byteoff >> 6;
      int k8 = (byteoff >> 4) & 3;
      int gb = col0 + r; gb = gb < N ? gb : N - 1;
      gload_lds16(BT + (size_t)gb * K + k0 + k8 * 8, &Bs[0][0] + it * 2048 + wv * 512);
    }
    if (AMODE == 0) {
#pragma unroll
      for (int it = 0; it < 2; ++it) {
        int byteoff = it * 4096 + wv * 1024 + ln * 16;
        int r = byteoff >> 6;
        int k8 = (byteoff >> 4) & 3;
        int gr = row0 + r; gr = gr < M ? gr : M - 1;
        gload_lds16((const __bf16*)A + aoff + (size_t)gr * K + k0 + k8 * 8,
                    &As[0][0] + it * 2048 + wv * 512);
      }
    } else {
      const int kk = k0 + skh;
      const float* Af;
      if (AMODE == 1) Af = (const float*)A + aoff + (size_t)sga * K + kk;
      else Af = (kk < 512) ? (zr + (size_t)pidx * 512 + kk)
                           : (zi + (size_t)oidx * 512 + (kk - 512));
      f32x4 v0 = *(const f32x4*)(Af + 0);
      f32x4 v1 = *(const f32x4*)(Af + 4);
      f32x4 v2 = *(const f32x4*)(Af + 8);
      f32x4 v3 = *(const f32x4*)(Af + 12);
      bf16x8 alo, ahi;
#pragma unroll
      for (int q = 0; q < 4; ++q) { alo[q] = (__bf16)v0[q]; alo[q + 4] = (__bf16)v1[q]; }
#pragma unroll
      for (int q = 0; q < 4; ++q) { ahi[q] = (__bf16)v2[q]; ahi[q + 4] = (__bf16)v3[q]; }
      *(bf16x8*)&As[srow][skh]     = alo;
      *(bf16x8*)&As[srow][skh + 8] = ahi;
    }
    __syncthreads();

    s16x8 af[4], bfr[4];
#pragma unroll
    for (int i = 0; i < 4; ++i)
      af[i] = *(const s16x8*)&As[wr * 64 + i * 16 + lrow][kgrp];
#pragma unroll
    for (int j = 0; j < 4; ++j)
      bfr[j] = *(const s16x8*)&Bs[wc * 64 + j * 16 + lrow][kgrp];
#pragma unroll
    for (int i = 0; i < 4; ++i)
#pragma unroll
      for (int j = 0; j < 4; ++j)
        acc[i][j] = __builtin_amdgcn_mfma_f32_16x16x32_bf16(af[i], bfr[j], acc[i][j], 0, 0, 0);
    __syncthreads();
  }

  float bv[4]; int bcol[4];
#pragma unroll
  for (int j = 0; j < 4; ++j) {
    bcol[j] = col0 + wc * 64 + j * 16 + lrow;
    bv[j] = (bcol[j] < N) ? bias[bcol[j]] : 0.f;
  }
  const int rbase = row0 + wr * 64 + (ln >> 4) * 4;
#pragma unroll
  for (int i = 0; i < 4; ++i) {
#pragma unroll
    for (int rr = 0; rr < 4; ++rr) {
      int r = rbase + i * 16 + rr;
      if (r < M) {
#pragma unroll
        for (int j = 0; j < 4; ++j) {
          if (bcol[j] < N) {
            float v = acc[i][j][rr] + bv[j];
            if (ACT == 1) v = (v >= 0.f) ? v : 0.01f * v;
            if (OSEL == 0) ((float*)Cc)[(size_t)r * N + bcol[j]] = v;
            else ((__bf16*)Cc)[(size_t)r * N + bcol[j]] = (__bf16)v;
          }
        }
      }
    }
  }
}

__global__ __launch_bounds__(256) void gather512_k(const float* __restrict__ zE,
                                                   const int* __restrict__ labels,
                                                   float* __restrict__ dst) {
  int b = blockIdx.x * 4 + (threadIdx.x >> 6);
  int ln = threadIdx.x & 63;
  int g = labels[b]; g = g < 0 ? 0 : (g > 31 ? 31 : g);
#pragma unroll
  for (int q = 0; q < 8; ++q)
    dst[(size_t)b * 512 + ln * 8 + q] = zE[(size_t)g * 512 + ln * 8 + q];
}

__global__ __launch_bounds__(256) void threefry_s_k(const int* __restrict__ labels,
                                                    float* __restrict__ s) {
  int i = blockIdx.x * blockDim.x + threadIdx.x;
  if (i >= Bn) return;
  unsigned x0 = 0u, x1 = (unsigned)i;
  tf2x32(0u, 1234u, x0, x1);
  unsigned bits = x0 ^ x1;
  float u = __uint_as_float((bits >> 9) | 0x3f800000u) - 1.0f;
  u = fmaxf(u, 0.0f);
  s[i] = (float)labels[i] + u;
}

__global__ __launch_bounds__(256) void rank_k(const int* __restrict__ labels,
                                              const float* __restrict__ s,
                                              int* __restrict__ order,
                                              int* __restrict__ perm) {
  __shared__ unsigned char Ls[8192];
  __shared__ float Ss[8192];
  for (int j = threadIdx.x; j < 8192; j += 256) {
    Ls[j] = (unsigned char)labels[j];
    Ss[j] = s[j];
  }
  __syncthreads();
  int i = blockIdx.x * 32 + (threadIdx.x >> 3);
  int part = threadIdx.x & 7;
  int li = Ls[i];
  float si = Ss[i];
  int ro = 0, rp = 0;
  for (int j = part * 1024; j < (part + 1) * 1024; ++j) {
    int lj = Ls[j];
    float sj = Ss[j];
    ro += (lj < li || (lj == li && j < i)) ? 1 : 0;
    rp += (sj < si || (sj == si && j < i)) ? 1 : 0;
  }
#pragma unroll
  for (int d = 4; d; d >>= 1) {
    ro += __shfl_down(ro, d);
    rp += __shfl_down(rp, d);
  }
  if (part == 0) {
    order[ro] = i;
    perm[rp] = i;
  }
}

__global__ __launch_bounds__(256) void persample_k(const float* __restrict__ out,
                                                   float* __restrict__ costT,
                                                   float* __restrict__ psamp) {
  int b = blockIdx.x * 4 + (threadIdx.x >> 6);
  int ln = threadIdx.x & 63;
  float dlr = 0.f, dli = 0.f, nl = 0.f, nr = 0.f, ni = 0.f;
#pragma unroll
  for (int q = 0; q < 8; ++q) {
    size_t idx = (size_t)b * 512 + ln * 8 + q;
    float fl = out[ZL_OFF + idx];
    float fr = out[ZR_OFF + idx];
    float fi = out[ZI_OFF + idx];
    dlr += fl * fr; dli += fl * fi;
    nl += fl * fl;  nr += fr * fr;  ni += fi * fi;
  }
#pragma unroll
  for (int off = 32; off; off >>= 1) {
    dlr += __shfl_down(dlr, off);
    dli += __shfl_down(dli, off);
    nl  += __shfl_down(nl,  off);
    nr  += __shfl_down(nr,  off);
    ni  += __shfl_down(ni,  off);
  }
  if (ln == 0) {
    float snl = sqrtf(nl), snr = sqrtf(nr), sni = sqrtf(ni);
    float cost = 1.0f - dlr / (fmaxf(snl, 1e-5f) * fmaxf(snr, 1e-5f));
    float cp = dlr / (fmaxf(snl, 1e-8f) * fmaxf(snr, 1e-8f));
    float cn = dli / (fmaxf(snl, 1e-8f) * fmaxf(sni, 1e-8f));
    float d = 1.5f * (cn - cp);
    float ps = (d > 0.f) ? d + log1pf(expf(-d)) : log1pf(expf(d));
    float a = expf(-cost * 2.0f), sg = 1.f, T = 1.f;
    for (int t = 0; t < 50; ++t) {
      float q = a * T;
      float dl = 1.f / (q * sg);
      sg = 1.f / (dl * q);
      T = dl * q * sg;
    }
    costT[b] = cost * T;
    psamp[b] = ps;
  }
}

__global__ __launch_bounds__(256) void ot_reduce_k(const float* __restrict__ costT,
                                                   float* __restrict__ out) {
  __shared__ float red[256];
  float sum = 0.f;
  for (int i = threadIdx.x; i < Bn; i += 256) sum += costT[i];
  red[threadIdx.x] = sum;
  __syncthreads();
  for (int st = 128; st; st >>= 1) {
    if (threadIdx.x < st) red[threadIdx.x] += red[threadIdx.x + st];
    __syncthreads();
  }
  if (threadIdx.x == 0) out[OT_OFF] = red[0] / (float)Bn;
}

__global__ __launch_bounds__(256) void group_reduce_k(const int* __restrict__ labels,
                                                      const float* __restrict__ psamp,
                                                      float* __restrict__ gmean,
                                                      float* __restrict__ present) {
  int g = blockIdx.x;
  __shared__ float rs[256];
  __shared__ int rc[256];
  float s = 0.f; int c = 0;
  for (int i = threadIdx.x; i < Bn; i += 256)
    if (labels[i] == g) { s += psamp[i]; c++; }
  rs[threadIdx.x] = s; rc[threadIdx.x] = c;
  __syncthreads();
  for (int st = 128; st; st >>= 1) {
    if (threadIdx.x < st) { rs[threadIdx.x] += rs[threadIdx.x + st]; rc[threadIdx.x] += rc[threadIdx.x + st]; }
    __syncthreads();
  }
  if (threadIdx.x == 0) {
    gmean[g] = rc[0] > 0 ? rs[0] / (float)rc[0] : 0.f;
    present[g] = rc[0] > 0 ? 1.f : 0.f;
  }
}

__global__ void contra_final_k(const float* __restrict__ gmean,
                               const float* __restrict__ present,
                               float* __restrict__ out) {
  if (threadIdx.x == 0) {
    float s = 0.f, p = 0.f;
    for (int g = 0; g < 32; ++g) { s += gmean[g]; p += present[g]; }
    out[CT_OFF] = s / p;
  }
}

__global__ __launch_bounds__(128) void xori_k(const float* __restrict__ x,
                                              const int* __restrict__ order,
                                              float* __restrict__ out) {
  int j = blockIdx.x, t = threadIdx.x;
  int o = order[j]; o = o < 0 ? 0 : (o > Bn - 1 ? Bn - 1 : o);
#pragma unroll
  for (int q = 0; q < 8; ++q)
    out[XO_OFF + (size_t)j * 1024 + t * 8 + q] = x[(size_t)o * 1024 + t * 8 + q];
}

// ---- BN partials: grid (32 colblk, 16 rowblk); each block reduces 128 rows ----
__global__ __launch_bounds__(256) void bnacc_k(const __bf16* __restrict__ h,
                                               float* __restrict__ sum,    // [slot][2048]
                                               float* __restrict__ sum2,
                                               int slotbase) {
  int colbase = blockIdx.x * 64;
  int rowbase = blockIdx.y * 128;
  int lc = threadIdx.x & 63, rg = threadIdx.x >> 6;
  float s = 0.f, s2 = 0.f;
  for (int r = rowbase + rg; r < rowbase + 128; r += 4) {
    float v = (float)h[(size_t)r * 2048 + colbase + lc];
    s += v; s2 += v * v;
  }
  __shared__ float sh[4][64], sh2[4][64];
  sh[rg][lc] = s; sh2[rg][lc] = s2;
  __syncthreads();
  if (rg == 0) {
    s  = sh[0][lc] + sh[1][lc] + sh[2][lc] + sh[3][lc];
    s2 = sh2[0][lc] + sh2[1][lc] + sh2[2][lc] + sh2[3][lc];
    int slot = slotbase + blockIdx.y;
    sum[(size_t)slot * 2048 + colbase + lc]  = s;
    sum2[(size_t)slot * 2048 + colbase + lc] = s2;
  }
}

__global__ __launch_bounds__(256) void bnfinal_k(const float* __restrict__ sumA,
                                                 const float* __restrict__ sum2A,
                                                 const float* __restrict__ gamma,
                                                 const float* __restrict__ beta,
                                                 float* __restrict__ scale,
                                                 float* __restrict__ shift) {
  int c = blockIdx.x * 256 + threadIdx.x;
  float s = 0.f, s2 = 0.f;
  for (int q = 0; q < 64; ++q) { s += sumA[(size_t)q * 2048 + c]; s2 += sum2A[(size_t)q * 2048 + c]; }
  float mu = s / (float)Bn;
  float var = s2 / (float)Bn - mu * mu;
  float sc = gamma[c] / sqrtf(var + 1e-5f);
  scale[c] = sc;
  shift[c] = beta[c] - mu * sc;
}

__global__ __launch_bounds__(256) void bnapply_k(__bf16* __restrict__ h,
                                                 const float* __restrict__ scale,
                                                 const float* __restrict__ shift) {
  size_t i = (size_t)blockIdx.x * 256 + threadIdx.x;
#pragma unroll
  for (int q = 0; q < 8; ++q) {
    size_t e = i * 8 + q;
    int col = (int)(e & 2047);
    float f = (float)h[e] * scale[col] + shift[col];
    f = (f >= 0.f) ? f : 0.01f * f;
    h[e] = (__bf16)f;
  }
}

__global__ void marker_k(float* __restrict__ p, float v) {
  if (threadIdx.x == 0) *p = v;
}

// ==================================================================================
extern "C" void kernel_launch(void* const* d_in, const int* in_sizes, int n_in,
                              void* d_out, int out_size, void* d_ws, size_t ws_size,
                              hipStream_t stream) {
  const float* x    = (const float*)d_in[0];
  const int*  labels = (const int*)d_in[1];
  const float* Wr1 = (const float*)d_in[2];  const float* br1 = (const float*)d_in[3];
  const float* Wr2 = (const float*)d_in[4];  const float* br2 = (const float*)d_in[5];
  const float* Wi1 = (const float*)d_in[6];  const float* bi1 = (const float*)d_in[7];
  const float* Wi2 = (const float*)d_in[8];  const float* bi2 = (const float*)d_in[9];
  const float* E   = (const float*)d_in[10];
  const float* Wd1 = (const float*)d_in[11]; const float* bd1 = (const float*)d_in[12];
  const float* Wd2 = (const float*)d_in[13]; const float* bd2 = (const float*)d_in[14];
  const float* Wc1 = (const float*)d_in[15]; const float* bc1 = (const float*)d_in[16];
  const float* bng = (const float*)d_in[17]; const float* bnb = (const float*)d_in[18];
  const float* Wc2 = (const float*)d_in[19]; const float* bc2 = (const float*)d_in[20];

  float* out = (float*)d_out;
  dim3 b256(256);
  const int* ni = nullptr;
  const float* nf = nullptr;
  void* nv = nullptr;

  if (ws_size < (1u << 20)) {
    marker_k<<<dim3(1), dim3(64), 0, stream>>>(out + XR_OFF, 110.f);
    return;
  }

  char* wsb = (char*)d_ws;
  float* sval   = (float*)(wsb);
  float* costT  = (float*)(wsb + 32768);
  float* psamp  = (float*)(wsb + 65536);
  int*   ordr   = (int*)  (wsb + 98304);
  int*   prm    = (int*)  (wsb + 131072);
  float* gmean  = (float*)(wsb + 164096);
  float* present= (float*)(wsb + 164224);
  float* bnscale= (float*)(wsb + 164352);
  float* bnshift= (float*)(wsb + 172544);
  __bf16* hE    = (__bf16*)(wsb + 246272);
  float*  zE    = (float*)(wsb + 377344);

  // Phase E scratch (f32 slots in dead x_ori region):
  __bf16* TAB  = (__bf16*)(out + SB_OFF);              // [4096][1024]
  __bf16* TB2  = (__bf16*)(out + SB_OFF + 2097152);    // [1024][2048]
  __bf16* hL   = (__bf16*)(out + SB_OFF + 3145728);    // [2048][2048]
  __bf16* hR   = (__bf16*)(out + SB_OFF + 5242880);    // [2048][2048]
  __bf16* xch  = (__bf16*)(out + SB_OFF + 7340032);    // [2048][1024]
  // Phase D/C scratch
  __bf16* TAd   = (__bf16*)(out + SB_OFF);             // [2048][1024]
  __bf16* TBd   = (__bf16*)(out + SB_OFF + 1048576);   // [1024][2048]
  __bf16* hbufd = (__bf16*)(out + SB_OFF + 2097152);   // [2048][2048]
  __bf16* TAc   = (__bf16*)(out + SB_OFF);             // [2048][512]
  __bf16* TBc   = (__bf16*)(out + SB_OFF + 524288);    // [32][2048]
  float* bnsum  = out + SB_OFF + 4194304;              // 64 slots x 2048 f32
  float* bnsum2 = out + SB_OFF + 4325376;              // 64 slots x 2048 f32

  // ---- merged encoders ----
  transpose_k<<<dim3(64, 32), b256, 0, stream>>>(Wr1, TAB, 1024, 2048);
  transpose_k<<<dim3(64, 32), b256, 0, stream>>>(Wi1, TAB + 2097152, 1024, 2048);
  transpose_k<<<dim3(16, 64), b256, 0, stream>>>(Wr2, TB2, 2048, 512);
  transpose_k<<<dim3(16, 64), b256, 0, stream>>>(Wi2, TB2 + 1048576, 2048, 512);
  for (int mc = 0; mc < 4; ++mc) {
    cvt_k<<<dim3(1024), b256, 0, stream>>>(x + (size_t)mc * 2097152, xch);
    mgemm_k<1,0,1><<<dim3(16, 16), b256, 0, stream>>>(xch, 0, TAB, br1, hL,
                                                      2048, 2048, 1024, ni, ni, nf, nf);
    mgemm_k<1,0,1><<<dim3(16, 16), b256, 0, stream>>>(xch, 0, TAB + 2097152, bi1, hR,
                                                      2048, 2048, 1024, ni, ni, nf, nf);
    mgemm_k<0,0,0><<<dim3(4, 16), b256, 0, stream>>>(hL, 0, TB2, br2,
                                                     out + ZR_OFF + (size_t)mc * 1048576,
                                                     2048, 512, 2048, ni, ni, nf, nf);
    mgemm_k<0,0,0><<<dim3(4, 16), b256, 0, stream>>>(hR, 0, TB2 + 1048576, bi2,
                                                     out + ZI_OFF + (size_t)mc * 1048576,
                                                     2048, 512, 2048, ni, ni, nf, nf);
  }
  // ---- label encoder + gather ----
  mgemm_k<1,1,1><<<dim3(16, 1), b256, 0, stream>>>(E, 0, TAB, br1, hE,
                                                   32, 2048, 1024, ni, ni, nf, nf);
  mgemm_k<0,0,0><<<dim3(4, 1), b256, 0, stream>>>(hE, 0, TB2, br2, zE,
                                                  32, 512, 2048, ni, ni, nf, nf);
  gather512_k<<<dim3(2048), b256, 0, stream>>>(zE, labels, out + ZL_OFF);

  // ---- permutations + per-sample losses ----
  threefry_s_k<<<dim3(32), b256, 0, stream>>>(labels, sval);
  rank_k<<<dim3(256), b256, 0, stream>>>(labels, sval, ordr, prm);
  persample_k<<<dim3(2048), b256, 0, stream>>>(out, costT, psamp);
  group_reduce_k<<<dim3(32), b256, 0, stream>>>(labels, psamp, gmean, present);

  // ---- decoder ----
  transpose_k<<<dim3(64, 32), b256, 0, stream>>>(Wd1, TAd, 1024, 2048);
  transpose_k<<<dim3(32, 64), b256, 0, stream>>>(Wd2, TBd, 2048, 1024);
  for (int mc = 0; mc < 4; ++mc) {
    mgemm_k<1,2,1><<<dim3(16, 16), b256, 0, stream>>>(
        nv, 0, TAd, bd1, hbufd, 2048, 2048, 1024,
        prm + mc * 2048, ordr + mc * 2048, out + ZR_OFF, out + ZI_OFF);
    mgemm_k<0,0,0><<<dim3(8, 16), b256, 0, stream>>>(hbufd, 0, TBd, bd2,
                                                     out + XR_OFF + (size_t)mc * 2097152,
                                                     2048, 1024, 2048, ni, ni, nf, nf);
  }

  // ---- classifier ----
  transpose_k<<<dim3(64, 16), b256, 0, stream>>>(Wc1, TAc, 512, 2048);
  transpose_k<<<dim3(1, 64), b256, 0, stream>>>(Wc2, TBc, 2048, 32);
  for (int mc = 0; mc < 4; ++mc) {
    mgemm_k<0,1,1><<<dim3(16, 16), b256, 0, stream>>>(out, ZR_OFF + (size_t)mc * 1048576,
                                                      TAc, bc1, hbufd,
                                                      2048, 2048, 512, ni, ni, nf, nf);
    bnacc_k<<<dim3(32, 16), b256, 0, stream>>>(hbufd, bnsum, bnsum2, mc * 16);
  }
  bnfinal_k<<<dim3(8), b256, 0, stream>>>(bnsum, bnsum2, bng, bnb, bnscale, bnshift);
  for (int mc = 0; mc < 4; ++mc) {
    mgemm_k<0,1,1><<<dim3(16, 16), b256, 0, stream>>>(out, ZR_OFF + (size_t)mc * 1048576,
                                                      TAc, bc1, hbufd,
                                                      2048, 2048, 512, ni, ni, nf, nf);
    bnapply_k<<<dim3(2048), b256, 0, stream>>>(hbufd, bnscale, bnshift);
    mgemm_k<0,0,0><<<dim3(1, 16), b256, 0, stream>>>(hbufd, 0, TBc, bc2,
                                                     out + LG_OFF + (size_t)mc * 65536,
                                                     2048, 32, 2048, ni, ni, nf, nf);
  }

  // ---- scalar finals, x_ori LAST ----
  ot_reduce_k<<<dim3(1), b256, 0, stream>>>(costT, out);
  contra_final_k<<<dim3(1), dim3(64), 0, stream>>>(gmean, present, out);
  xori_k<<<dim3(8192), dim3(128), 0, stream>>>(x, ordr, out);

  (void)in_sizes; (void)n_in; (void)out_size;
}

// Round 21
// 1311.562 us; speedup vs baseline: 7.4635x; 1.5299x over previous
//
#include <hip/hip_runtime.h>

typedef short  s16x8 __attribute__((ext_vector_type(8)));
typedef __bf16 bf16x8 __attribute__((ext_vector_type(8)));
typedef float  f32x4 __attribute__((ext_vector_type(4)));

static constexpr int Bn = 8192;
static constexpr size_t XR_OFF = 0;
static constexpr size_t ZL_OFF = 8388608;
static constexpr size_t ZR_OFF = 12582912;
static constexpr size_t ZI_OFF = 16777216;
static constexpr size_t OT_OFF = 20971520;
static constexpr size_t XO_OFF = 20971521;
static constexpr size_t CT_OFF = 29360129;
static constexpr size_t LG_OFF = 29360130;
static constexpr size_t SB_OFF = 20971522;

struct ZP {
  const void* Az[2];
  size_t aoff[2];
  const __bf16* BTz[2];
  const float* biasz[2];
  void* Cz[2];
};

__device__ __forceinline__ void gload_lds16(const void* g, void* l) {
  __builtin_amdgcn_global_load_lds((const __attribute__((address_space(1))) void*)g,
                                   (__attribute__((address_space(3))) void*)l, 16, 0, 0);
}

__device__ __forceinline__ void tf2x32(unsigned k0, unsigned k1, unsigned& x0, unsigned& x1) {
  const unsigned ks[3] = {k0, k1, k0 ^ k1 ^ 0x1BD11BDAu};
  x0 += ks[0]; x1 += ks[1];
  const int R1r[4] = {13, 15, 26, 6}, R2r[4] = {17, 29, 16, 24};
#pragma unroll
  for (int g = 0; g < 5; ++g) {
    const int* rr = (g & 1) ? R2r : R1r;
#pragma unroll
    for (int q = 0; q < 4; ++q) {
      x0 += x1;
      x1 = (x1 << rr[q]) | (x1 >> (32 - rr[q]));
      x1 ^= x0;
    }
    x0 += ks[(g + 1) % 3];
    x1 += ks[(g + 2) % 3] + (unsigned)(g + 1);
  }
}

__global__ __launch_bounds__(256) void transpose_k(const float* __restrict__ in,
                                                   __bf16* __restrict__ out,
                                                   int R, int C) {
  __shared__ float t[32][33];
  int c0 = blockIdx.x * 32, r0 = blockIdx.y * 32;
  int lc = threadIdx.x & 31, lr = threadIdx.x >> 5;
#pragma unroll
  for (int i = 0; i < 4; ++i) {
    int r = lr + i * 8;
    t[r][lc] = in[(size_t)(r0 + r) * C + c0 + lc];
  }
  __syncthreads();
#pragma unroll
  for (int i = 0; i < 4; ++i) {
    int cc = lr + i * 8;
    out[(size_t)(c0 + cc) * R + r0 + lc] = (__bf16)t[lc][cc];
  }
}

__global__ __launch_bounds__(256) void cvt_k(const float* __restrict__ in,
                                             __bf16* __restrict__ out) {
  size_t i = ((size_t)blockIdx.x * 256 + threadIdx.x) * 8;
  f32x4 v0 = *(const f32x4*)(in + i);
  f32x4 v1 = *(const f32x4*)(in + i + 4);
  bf16x8 o;
#pragma unroll
  for (int q = 0; q < 4; ++q) { o[q] = (__bf16)v0[q]; o[q + 4] = (__bf16)v1[q]; }
  *(bf16x8*)(out + i) = o;
}

// ---- MFMA GEMM: C = act(A @ BT^T + bias), 128x128 tile, BK=32, blockIdx.z-select ----
// AMODE: 0 = A bf16 (global_load_lds, row stride lda); 1 = A f32 (reg-cvt, stride lda);
//        2 = gather concat(zr[prm],zi[ord]).  OSEL: 0 = C f32; 1 = C bf16.
// BSPLIT: bias for col<2048, bias2 for col>=2048.
template <int ACT, int AMODE, int OSEL, int BSPLIT>
__global__ __launch_bounds__(256) void mgemm_k(ZP zp, const float* __restrict__ bias2,
                                               int M, int N, int K, int lda,
                                               const int* __restrict__ prmq,
                                               const int* __restrict__ ordq,
                                               const float* __restrict__ zr,
                                               const float* __restrict__ zi) {
  const int zsel = blockIdx.z;
  const void* A = zp.Az[zsel];
  const size_t aoff = zp.aoff[zsel];
  const __bf16* BT = zp.BTz[zsel];
  const float* bias = zp.biasz[zsel];
  void* Cc = zp.Cz[zsel];

  __shared__ __bf16 As[128][32];
  __shared__ __bf16 Bs[128][32];
  const int tid = threadIdx.x;
  const int wv = tid >> 6, ln = tid & 63;
  const int row0 = blockIdx.y * 128, col0 = blockIdx.x * 128;
  const int wr = wv >> 1, wc = wv & 1;
  const int lrow = ln & 15;
  const int kgrp = (ln >> 4) * 8;
  const int srow = tid >> 1;
  const int skh  = (tid & 1) * 16;

  f32x4 acc[4][4] = {};

  int sga = row0 + srow; sga = sga < M ? sga : M - 1;
  int pidx = 0, oidx = 0;
  if (AMODE == 2) {
    pidx = prmq[sga]; pidx = pidx < 0 ? 0 : (pidx > Bn - 1 ? Bn - 1 : pidx);
    oidx = ordq[sga]; oidx = oidx < 0 ? 0 : (oidx > Bn - 1 ? Bn - 1 : oidx);
  }

  for (int k0 = 0; k0 < K; k0 += 32) {
#pragma unroll
    for (int it = 0; it < 2; ++it) {
      int byteoff = it * 4096 + wv * 1024 + ln * 16;
      int r = byteoff >> 6;
      int k8 = (byteoff >> 4) & 3;
      int gb = col0 + r; gb = gb < N ? gb : N - 1;
      gload_lds16(BT + (size_t)gb * K + k0 + k8 * 8, &Bs[0][0] + it * 2048 + wv * 512);
    }
    if (AMODE == 0) {
#pragma unroll
      for (int it = 0; it < 2; ++it) {
        int byteoff = it * 4096 + wv * 1024 + ln * 16;
        int r = byteoff >> 6;
        int k8 = (byteoff >> 4) & 3;
        int gr = row0 + r; gr = gr < M ? gr : M - 1;
        gload_lds16((const __bf16*)A + aoff + (size_t)gr * lda + k0 + k8 * 8,
                    &As[0][0] + it * 2048 + wv * 512);
      }
    } else {
      const int kk = k0 + skh;
      const float* Af;
      if (AMODE == 1) Af = (const float*)A + aoff + (size_t)sga * lda + kk;
      else Af = (kk < 512) ? (zr + (size_t)pidx * 512 + kk)
                           : (zi + (size_t)oidx * 512 + (kk - 512));
      f32x4 v0 = *(const f32x4*)(Af + 0);
      f32x4 v1 = *(const f32x4*)(Af + 4);
      f32x4 v2 = *(const f32x4*)(Af + 8);
      f32x4 v3 = *(const f32x4*)(Af + 12);
      bf16x8 alo, ahi;
#pragma unroll
      for (int q = 0; q < 4; ++q) { alo[q] = (__bf16)v0[q]; alo[q + 4] = (__bf16)v1[q]; }
#pragma unroll
      for (int q = 0; q < 4; ++q) { ahi[q] = (__bf16)v2[q]; ahi[q + 4] = (__bf16)v3[q]; }
      *(bf16x8*)&As[srow][skh]     = alo;
      *(bf16x8*)&As[srow][skh + 8] = ahi;
    }
    __syncthreads();

    s16x8 af[4], bfr[4];
#pragma unroll
    for (int i = 0; i < 4; ++i)
      af[i] = *(const s16x8*)&As[wr * 64 + i * 16 + lrow][kgrp];
#pragma unroll
    for (int j = 0; j < 4; ++j)
      bfr[j] = *(const s16x8*)&Bs[wc * 64 + j * 16 + lrow][kgrp];
#pragma unroll
    for (int i = 0; i < 4; ++i)
#pragma unroll
      for (int j = 0; j < 4; ++j)
        acc[i][j] = __builtin_amdgcn_mfma_f32_16x16x32_bf16(af[i], bfr[j], acc[i][j], 0, 0, 0);
    __syncthreads();
  }

  float bv[4]; int bcol[4];
#pragma unroll
  for (int j = 0; j < 4; ++j) {
    bcol[j] = col0 + wc * 64 + j * 16 + lrow;
    if (BSPLIT) bv[j] = (bcol[j] < 2048) ? bias[bcol[j]] : bias2[bcol[j] - 2048];
    else bv[j] = (bcol[j] < N) ? bias[bcol[j]] : 0.f;
  }
  const int rbase = row0 + wr * 64 + (ln >> 4) * 4;
#pragma unroll
  for (int i = 0; i < 4; ++i) {
#pragma unroll
    for (int rr = 0; rr < 4; ++rr) {
      int r = rbase + i * 16 + rr;
      if (r < M) {
#pragma unroll
        for (int j = 0; j < 4; ++j) {
          if (bcol[j] < N) {
            float v = acc[i][j][rr] + bv[j];
            if (ACT == 1) v = (v >= 0.f) ? v : 0.01f * v;
            if (OSEL == 0) ((float*)Cc)[(size_t)r * N + bcol[j]] = v;
            else ((__bf16*)Cc)[(size_t)r * N + bcol[j]] = (__bf16)v;
          }
        }
      }
    }
  }
}

__global__ __launch_bounds__(256) void gather512_k(const float* __restrict__ zE,
                                                   const int* __restrict__ labels,
                                                   float* __restrict__ dst) {
  int b = blockIdx.x * 4 + (threadIdx.x >> 6);
  int ln = threadIdx.x & 63;
  int g = labels[b]; g = g < 0 ? 0 : (g > 31 ? 31 : g);
#pragma unroll
  for (int q = 0; q < 8; ++q)
    dst[(size_t)b * 512 + ln * 8 + q] = zE[(size_t)g * 512 + ln * 8 + q];
}

__global__ __launch_bounds__(256) void threefry_s_k(const int* __restrict__ labels,
                                                    float* __restrict__ s) {
  int i = blockIdx.x * blockDim.x + threadIdx.x;
  if (i >= Bn) return;
  unsigned x0 = 0u, x1 = (unsigned)i;
  tf2x32(0u, 1234u, x0, x1);
  unsigned bits = x0 ^ x1;
  float u = __uint_as_float((bits >> 9) | 0x3f800000u) - 1.0f;
  u = fmaxf(u, 0.0f);
  s[i] = (float)labels[i] + u;
}

__global__ __launch_bounds__(256) void rank_k(const int* __restrict__ labels,
                                              const float* __restrict__ s,
                                              int* __restrict__ order,
                                              int* __restrict__ perm) {
  __shared__ unsigned char Ls[8192];
  __shared__ float Ss[8192];
  for (int j = threadIdx.x; j < 8192; j += 256) {
    Ls[j] = (unsigned char)labels[j];
    Ss[j] = s[j];
  }
  __syncthreads();
  int i = blockIdx.x * 32 + (threadIdx.x >> 3);
  int part = threadIdx.x & 7;
  int li = Ls[i];
  float si = Ss[i];
  int ro = 0, rp = 0;
  for (int j = part * 1024; j < (part + 1) * 1024; ++j) {
    int lj = Ls[j];
    float sj = Ss[j];
    ro += (lj < li || (lj == li && j < i)) ? 1 : 0;
    rp += (sj < si || (sj == si && j < i)) ? 1 : 0;
  }
#pragma unroll
  for (int d = 4; d; d >>= 1) {
    ro += __shfl_down(ro, d);
    rp += __shfl_down(rp, d);
  }
  if (part == 0) {
    order[ro] = i;
    perm[rp] = i;
  }
}

__global__ __launch_bounds__(256) void persample_k(const float* __restrict__ out,
                                                   float* __restrict__ costT,
                                                   float* __restrict__ psamp) {
  int b = blockIdx.x * 4 + (threadIdx.x >> 6);
  int ln = threadIdx.x & 63;
  float dlr = 0.f, dli = 0.f, nl = 0.f, nr = 0.f, ni = 0.f;
#pragma unroll
  for (int q = 0; q < 8; ++q) {
    size_t idx = (size_t)b * 512 + ln * 8 + q;
    float fl = out[ZL_OFF + idx];
    float fr = out[ZR_OFF + idx];
    float fi = out[ZI_OFF + idx];
    dlr += fl * fr; dli += fl * fi;
    nl += fl * fl;  nr += fr * fr;  ni += fi * fi;
  }
#pragma unroll
  for (int off = 32; off; off >>= 1) {
    dlr += __shfl_down(dlr, off);
    dli += __shfl_down(dli, off);
    nl  += __shfl_down(nl,  off);
    nr  += __shfl_down(nr,  off);
    ni  += __shfl_down(ni,  off);
  }
  if (ln == 0) {
    float snl = sqrtf(nl), snr = sqrtf(nr), sni = sqrtf(ni);
    float cost = 1.0f - dlr / (fmaxf(snl, 1e-5f) * fmaxf(snr, 1e-5f));
    float cp = dlr / (fmaxf(snl, 1e-8f) * fmaxf(snr, 1e-8f));
    float cn = dli / (fmaxf(snl, 1e-8f) * fmaxf(sni, 1e-8f));
    float d = 1.5f * (cn - cp);
    float ps = (d > 0.f) ? d + log1pf(expf(-d)) : log1pf(expf(d));
    float a = expf(-cost * 2.0f), sg = 1.f, T = 1.f;
    for (int t = 0; t < 50; ++t) {
      float q = a * T;
      float dl = 1.f / (q * sg);
      sg = 1.f / (dl * q);
      T = dl * q * sg;
    }
    costT[b] = cost * T;
    psamp[b] = ps;
  }
}

__global__ __launch_bounds__(256) void ot_reduce_k(const float* __restrict__ costT,
                                                   float* __restrict__ out) {
  __shared__ float red[256];
  float sum = 0.f;
  for (int i = threadIdx.x; i < Bn; i += 256) sum += costT[i];
  red[threadIdx.x] = sum;
  __syncthreads();
  for (int st = 128; st; st >>= 1) {
    if (threadIdx.x < st) red[threadIdx.x] += red[threadIdx.x + st];
    __syncthreads();
  }
  if (threadIdx.x == 0) out[OT_OFF] = red[0] / (float)Bn;
}

__global__ __launch_bounds__(256) void group_reduce_k(const int* __restrict__ labels,
                                                      const float* __restrict__ psamp,
                                                      float* __restrict__ gmean,
                                                      float* __restrict__ present) {
  int g = blockIdx.x;
  __shared__ float rs[256];
  __shared__ int rc[256];
  float s = 0.f; int c = 0;
  for (int i = threadIdx.x; i < Bn; i += 256)
    if (labels[i] == g) { s += psamp[i]; c++; }
  rs[threadIdx.x] = s; rc[threadIdx.x] = c;
  __syncthreads();
  for (int st = 128; st; st >>= 1) {
    if (threadIdx.x < st) { rs[threadIdx.x] += rs[threadIdx.x + st]; rc[threadIdx.x] += rc[threadIdx.x + st]; }
    __syncthreads();
  }
  if (threadIdx.x == 0) {
    gmean[g] = rc[0] > 0 ? rs[0] / (float)rc[0] : 0.f;
    present[g] = rc[0] > 0 ? 1.f : 0.f;
  }
}

__global__ void contra_final_k(const float* __restrict__ gmean,
                               const float* __restrict__ present,
                               float* __restrict__ out) {
  if (threadIdx.x == 0) {
    float s = 0.f, p = 0.f;
    for (int g = 0; g < 32; ++g) { s += gmean[g]; p += present[g]; }
    out[CT_OFF] = s / p;
  }
}

__global__ __launch_bounds__(128) void xori_k(const float* __restrict__ x,
                                              const int* __restrict__ order,
                                              float* __restrict__ out) {
  int j = blockIdx.x, t = threadIdx.x;
  int o = order[j]; o = o < 0 ? 0 : (o > Bn - 1 ? Bn - 1 : o);
#pragma unroll
  for (int q = 0; q < 8; ++q)
    out[XO_OFF + (size_t)j * 1024 + t * 8 + q] = x[(size_t)o * 1024 + t * 8 + q];
}

__global__ __launch_bounds__(256) void bnacc_k(const __bf16* __restrict__ h,
                                               float* __restrict__ sum,
                                               float* __restrict__ sum2,
                                               int slotbase) {
  int colbase = blockIdx.x * 64;
  int rowbase = blockIdx.y * 256;
  int lc = threadIdx.x & 63, rg = threadIdx.x >> 6;
  float s = 0.f, s2 = 0.f;
  for (int r = rowbase + rg; r < rowbase + 256; r += 4) {
    float v = (float)h[(size_t)r * 2048 + colbase + lc];
    s += v; s2 += v * v;
  }
  __shared__ float sh[4][64], sh2[4][64];
  sh[rg][lc] = s; sh2[rg][lc] = s2;
  __syncthreads();
  if (rg == 0) {
    s  = sh[0][lc] + sh[1][lc] + sh[2][lc] + sh[3][lc];
    s2 = sh2[0][lc] + sh2[1][lc] + sh2[2][lc] + sh2[3][lc];
    int slot = slotbase + blockIdx.y;
    sum[(size_t)slot * 2048 + colbase + lc]  = s;
    sum2[(size_t)slot * 2048 + colbase + lc] = s2;
  }
}

__global__ __launch_bounds__(256) void bnfinal_k(const float* __restrict__ sumA,
                                                 const float* __restrict__ sum2A,
                                                 const float* __restrict__ gamma,
                                                 const float* __restrict__ beta,
                                                 float* __restrict__ scale,
                                                 float* __restrict__ shift) {
  int c = blockIdx.x * 256 + threadIdx.x;
  float s = 0.f, s2 = 0.f;
  for (int q = 0; q < 32; ++q) { s += sumA[(size_t)q * 2048 + c]; s2 += sum2A[(size_t)q * 2048 + c]; }
  float mu = s / (float)Bn;
  float var = s2 / (float)Bn - mu * mu;
  float sc = gamma[c] / sqrtf(var + 1e-5f);
  scale[c] = sc;
  shift[c] = beta[c] - mu * sc;
}

__global__ __launch_bounds__(256) void bnapply_k(__bf16* __restrict__ h,
                                                 const float* __restrict__ scale,
                                                 const float* __restrict__ shift) {
  size_t i = (size_t)blockIdx.x * 256 + threadIdx.x;
#pragma unroll
  for (int q = 0; q < 8; ++q) {
    size_t e = i * 8 + q;
    int col = (int)(e & 2047);
    float f = (float)h[e] * scale[col] + shift[col];
    f = (f >= 0.f) ? f : 0.01f * f;
    h[e] = (__bf16)f;
  }
}

__global__ void marker_k(float* __restrict__ p, float v) {
  if (threadIdx.x == 0) *p = v;
}

// ==================================================================================
extern "C" void kernel_launch(void* const* d_in, const int* in_sizes, int n_in,
                              void* d_out, int out_size, void* d_ws, size_t ws_size,
                              hipStream_t stream) {
  const float* x    = (const float*)d_in[0];
  const int*  labels = (const int*)d_in[1];
  const float* Wr1 = (const float*)d_in[2];  const float* br1 = (const float*)d_in[3];
  const float* Wr2 = (const float*)d_in[4];  const float* br2 = (const float*)d_in[5];
  const float* Wi1 = (const float*)d_in[6];  const float* bi1 = (const float*)d_in[7];
  const float* Wi2 = (const float*)d_in[8];  const float* bi2 = (const float*)d_in[9];
  const float* E   = (const float*)d_in[10];
  const float* Wd1 = (const float*)d_in[11]; const float* bd1 = (const float*)d_in[12];
  const float* Wd2 = (const float*)d_in[13]; const float* bd2 = (const float*)d_in[14];
  const float* Wc1 = (const float*)d_in[15]; const float* bc1 = (const float*)d_in[16];
  const float* bng = (const float*)d_in[17]; const float* bnb = (const float*)d_in[18];
  const float* Wc2 = (const float*)d_in[19]; const float* bc2 = (const float*)d_in[20];

  float* out = (float*)d_out;
  dim3 b256(256);
  const int* ni = nullptr;
  const float* nf = nullptr;

  if (ws_size < (1u << 20)) {
    marker_k<<<dim3(1), dim3(64), 0, stream>>>(out + XR_OFF, 110.f);
    return;
  }

  char* wsb = (char*)d_ws;
  float* sval   = (float*)(wsb);
  float* costT  = (float*)(wsb + 32768);
  float* psamp  = (float*)(wsb + 65536);
  int*   ordr   = (int*)  (wsb + 98304);
  int*   prm    = (int*)  (wsb + 131072);
  float* gmean  = (float*)(wsb + 164096);
  float* present= (float*)(wsb + 164224);
  float* bnscale= (float*)(wsb + 164352);
  float* bnshift= (float*)(wsb + 172544);
  float* bnsum  = (float*)(wsb + 180736);   // 32 slots x 2048 f32 = 256 KB
  float* bnsum2 = (float*)(wsb + 442880);   // 256 KB
  __bf16* hE    = (__bf16*)(wsb + 705024);  // 32x2048 bf16 = 128 KB
  float*  zE    = (float*)(wsb + 836096);   // 32x512 f32 = 64 KB

  // ---- scratch in dead x_ori region (f32 slot offsets; zone = 8,388,607 slots) ----
  // Phase E: TAB[0,2M) TB2[2M,3M) xch[3M,4M) hLR[4M,8M) (1-slot spill onto CT, rewritten)
  __bf16* TAB  = (__bf16*)(out + SB_OFF);              // [4096][1024] bf16
  __bf16* TB2  = (__bf16*)(out + SB_OFF + 2097152);    // [1024][2048] bf16
  __bf16* xch  = (__bf16*)(out + SB_OFF + 3145728);    // [2048][1024] bf16
  __bf16* hLR  = (__bf16*)(out + SB_OFF + 4194304);    // [2048][4096] bf16
  // Phase D: TAd[0,1M) TBd[1M,2M) hb0[2M,4M) hb1[4M,6M)   (FIXED layout)
  __bf16* TAd  = (__bf16*)(out + SB_OFF);              // [2048][1024] bf16 = 1M slots
  __bf16* TBd  = (__bf16*)(out + SB_OFF + 1048576);    // [1024][2048] bf16 = 1M slots
  __bf16* hb0  = (__bf16*)(out + SB_OFF + 2097152);    // [2048][2048] bf16 = 2M slots
  __bf16* hb1  = (__bf16*)(out + SB_OFF + 4194304);    // 2M slots
  // Phase C: TAc[0,0.5M) TBc[0.5M,+32K) hc0[1M,3M) hc1[3M,5M)
  __bf16* TAc  = (__bf16*)(out + SB_OFF);              // [2048][512] bf16 = 0.5M slots
  __bf16* TBc  = (__bf16*)(out + SB_OFF + 524288);     // [32][2048] bf16 = 32K slots
  __bf16* hc0  = (__bf16*)(out + SB_OFF + 1048576);    // 2M slots
  __bf16* hc1  = (__bf16*)(out + SB_OFF + 3145728);    // 2M slots

  auto zp1 = [](const void* A, size_t aoff, const __bf16* BT, const float* b, void* C) {
    ZP z; z.Az[0] = z.Az[1] = A; z.aoff[0] = z.aoff[1] = aoff;
    z.BTz[0] = z.BTz[1] = BT; z.biasz[0] = z.biasz[1] = b; z.Cz[0] = z.Cz[1] = C; return z;
  };
  auto zp2 = [](const void* A0, const void* A1, size_t o0, size_t o1,
                const __bf16* B0, const __bf16* B1, const float* b0, const float* b1,
                void* C0, void* C1) {
    ZP z; z.Az[0] = A0; z.Az[1] = A1; z.aoff[0] = o0; z.aoff[1] = o1;
    z.BTz[0] = B0; z.BTz[1] = B1; z.biasz[0] = b0; z.biasz[1] = b1;
    z.Cz[0] = C0; z.Cz[1] = C1; return z;
  };

  // ---- merged encoders ----
  transpose_k<<<dim3(64, 32), b256, 0, stream>>>(Wr1, TAB, 1024, 2048);
  transpose_k<<<dim3(64, 32), b256, 0, stream>>>(Wi1, TAB + 2097152, 1024, 2048);
  transpose_k<<<dim3(16, 64), b256, 0, stream>>>(Wr2, TB2, 2048, 512);
  transpose_k<<<dim3(16, 64), b256, 0, stream>>>(Wi2, TB2 + 1048576, 2048, 512);
  for (int mc = 0; mc < 4; ++mc) {
    cvt_k<<<dim3(1024), b256, 0, stream>>>(x + (size_t)mc * 2097152, xch);
    mgemm_k<1,0,1,1><<<dim3(32, 16, 1), b256, 0, stream>>>(
        zp1(xch, 0, TAB, br1, hLR), bi1, 2048, 4096, 1024, 1024, ni, ni, nf, nf);
    mgemm_k<0,0,0,0><<<dim3(4, 16, 2), b256, 0, stream>>>(
        zp2(hLR, hLR, 0, 2048, TB2, TB2 + 1048576, br2, bi2,
            out + ZR_OFF + (size_t)mc * 1048576, out + ZI_OFF + (size_t)mc * 1048576),
        nf, 2048, 512, 2048, 4096, ni, ni, nf, nf);
  }
  // ---- label encoder + gather ----
  mgemm_k<1,1,1,0><<<dim3(16, 1, 1), b256, 0, stream>>>(
      zp1(E, 0, TAB, br1, hE), nf, 32, 2048, 1024, 1024, ni, ni, nf, nf);
  mgemm_k<0,0,0,0><<<dim3(4, 1, 1), b256, 0, stream>>>(
      zp1(hE, 0, TB2, br2, zE), nf, 32, 512, 2048, 2048, ni, ni, nf, nf);
  gather512_k<<<dim3(2048), b256, 0, stream>>>(zE, labels, out + ZL_OFF);

  // ---- permutations + per-sample losses ----
  threefry_s_k<<<dim3(32), b256, 0, stream>>>(labels, sval);
  rank_k<<<dim3(256), b256, 0, stream>>>(labels, sval, ordr, prm);
  persample_k<<<dim3(2048), b256, 0, stream>>>(out, costT, psamp);
  group_reduce_k<<<dim3(32), b256, 0, stream>>>(labels, psamp, gmean, present);

  // ---- decoder (2 chunk-pairs) ----
  transpose_k<<<dim3(64, 32), b256, 0, stream>>>(Wd1, TAd, 1024, 2048);
  transpose_k<<<dim3(32, 64), b256, 0, stream>>>(Wd2, TBd, 2048, 1024);
  for (int mp = 0; mp < 2; ++mp) {
    int c0 = 2 * mp, c1 = 2 * mp + 1;
    mgemm_k<1,2,1,0><<<dim3(16, 16, 1), b256, 0, stream>>>(
        zp1(nullptr, 0, TAd, bd1, hb0), nf, 2048, 2048, 1024, 0,
        prm + c0 * 2048, ordr + c0 * 2048, out + ZR_OFF, out + ZI_OFF);
    mgemm_k<1,2,1,0><<<dim3(16, 16, 1), b256, 0, stream>>>(
        zp1(nullptr, 0, TAd, bd1, hb1), nf, 2048, 2048, 1024, 0,
        prm + c1 * 2048, ordr + c1 * 2048, out + ZR_OFF, out + ZI_OFF);
    mgemm_k<0,0,0,0><<<dim3(8, 16, 2), b256, 0, stream>>>(
        zp2(hb0, hb1, 0, 0, TBd, TBd, bd2, bd2,
            out + XR_OFF + (size_t)c0 * 2097152, out + XR_OFF + (size_t)c1 * 2097152),
        nf, 2048, 1024, 2048, 2048, ni, ni, nf, nf);
  }

  // ---- classifier (2 chunk-pairs, two passes) ----
  transpose_k<<<dim3(64, 16), b256, 0, stream>>>(Wc1, TAc, 512, 2048);
  transpose_k<<<dim3(1, 64), b256, 0, stream>>>(Wc2, TBc, 2048, 32);
  for (int mp = 0; mp < 2; ++mp) {
    int c0 = 2 * mp, c1 = 2 * mp + 1;
    mgemm_k<0,1,1,0><<<dim3(16, 16, 2), b256, 0, stream>>>(
        zp2(out + ZR_OFF + (size_t)c0 * 1048576, out + ZR_OFF + (size_t)c1 * 1048576,
            0, 0, TAc, TAc, bc1, bc1, hc0, hc1),
        nf, 2048, 2048, 512, 512, ni, ni, nf, nf);
    bnacc_k<<<dim3(32, 8), b256, 0, stream>>>(hc0, bnsum, bnsum2, c0 * 8);
    bnacc_k<<<dim3(32, 8), b256, 0, stream>>>(hc1, bnsum, bnsum2, c1 * 8);
  }
  bnfinal_k<<<dim3(8), b256, 0, stream>>>(bnsum, bnsum2, bng, bnb, bnscale, bnshift);
  for (int mp = 0; mp < 2; ++mp) {
    int c0 = 2 * mp, c1 = 2 * mp + 1;
    mgemm_k<0,1,1,0><<<dim3(16, 16, 2), b256, 0, stream>>>(
        zp2(out + ZR_OFF + (size_t)c0 * 1048576, out + ZR_OFF + (size_t)c1 * 1048576,
            0, 0, TAc, TAc, bc1, bc1, hc0, hc1),
        nf, 2048, 2048, 512, 512, ni, ni, nf, nf);
    bnapply_k<<<dim3(2048), b256, 0, stream>>>(hc0, bnscale, bnshift);
    bnapply_k<<<dim3(2048), b256, 0, stream>>>(hc1, bnscale, bnshift);
    mgemm_k<0,0,0,0><<<dim3(1, 16, 2), b256, 0, stream>>>(
        zp2(hc0, hc1, 0, 0, TBc, TBc, bc2, bc2,
            out + LG_OFF + (size_t)c0 * 65536, out + LG_OFF + (size_t)c1 * 65536),
        nf, 2048, 32, 2048, 2048, ni, ni, nf, nf);
  }

  // ---- scalar finals, x_ori LAST ----
  ot_reduce_k<<<dim3(1), b256, 0, stream>>>(costT, out);
  contra_final_k<<<dim3(1), dim3(64), 0, stream>>>(gmean, present, out);
  xori_k<<<dim3(8192), dim3(128), 0, stream>>>(x, ordr, out);

  (void)in_sizes; (void)n_in; (void)out_size;
}

// Round 22
// 1045.236 us; speedup vs baseline: 9.3652x; 1.2548x over previous
//
#include <hip/hip_runtime.h>

typedef short  s16x8 __attribute__((ext_vector_type(8)));
typedef __bf16 bf16x8 __attribute__((ext_vector_type(8)));
typedef float  f32x4 __attribute__((ext_vector_type(4)));

static constexpr int Bn = 8192;
static constexpr size_t XR_OFF = 0;
static constexpr size_t ZL_OFF = 8388608;
static constexpr size_t ZR_OFF = 12582912;
static constexpr size_t ZI_OFF = 16777216;
static constexpr size_t OT_OFF = 20971520;
static constexpr size_t XO_OFF = 20971521;
static constexpr size_t CT_OFF = 29360129;
static constexpr size_t LG_OFF = 29360130;
static constexpr size_t SB_OFF = 20971522;

struct ZP {
  const void* Az[2];
  size_t aoff[2];
  const __bf16* BTz[2];
  const float* biasz[2];
  void* Cz[2];
};

__device__ __forceinline__ void gload_lds16(const void* g, void* l) {
  __builtin_amdgcn_global_load_lds((const __attribute__((address_space(1))) void*)g,
                                   (__attribute__((address_space(3))) void*)l, 16, 0, 0);
}

__device__ __forceinline__ void tf2x32(unsigned k0, unsigned k1, unsigned& x0, unsigned& x1) {
  const unsigned ks[3] = {k0, k1, k0 ^ k1 ^ 0x1BD11BDAu};
  x0 += ks[0]; x1 += ks[1];
  const int R1r[4] = {13, 15, 26, 6}, R2r[4] = {17, 29, 16, 24};
#pragma unroll
  for (int g = 0; g < 5; ++g) {
    const int* rr = (g & 1) ? R2r : R1r;
#pragma unroll
    for (int q = 0; q < 4; ++q) {
      x0 += x1;
      x1 = (x1 << rr[q]) | (x1 >> (32 - rr[q]));
      x1 ^= x0;
    }
    x0 += ks[(g + 1) % 3];
    x1 += ks[(g + 2) % 3] + (unsigned)(g + 1);
  }
}

__global__ __launch_bounds__(256) void transpose_k(const float* __restrict__ in,
                                                   __bf16* __restrict__ out,
                                                   int R, int C) {
  __shared__ float t[32][33];
  int c0 = blockIdx.x * 32, r0 = blockIdx.y * 32;
  int lc = threadIdx.x & 31, lr = threadIdx.x >> 5;
#pragma unroll
  for (int i = 0; i < 4; ++i) {
    int r = lr + i * 8;
    t[r][lc] = in[(size_t)(r0 + r) * C + c0 + lc];
  }
  __syncthreads();
#pragma unroll
  for (int i = 0; i < 4; ++i) {
    int cc = lr + i * 8;
    out[(size_t)(c0 + cc) * R + r0 + lc] = (__bf16)t[lc][cc];
  }
}

__global__ __launch_bounds__(256) void cvt_k(const float* __restrict__ in,
                                             __bf16* __restrict__ out) {
  size_t i = ((size_t)blockIdx.x * 256 + threadIdx.x) * 8;
  f32x4 v0 = *(const f32x4*)(in + i);
  f32x4 v1 = *(const f32x4*)(in + i + 4);
  bf16x8 o;
#pragma unroll
  for (int q = 0; q < 4; ++q) { o[q] = (__bf16)v0[q]; o[q + 4] = (__bf16)v1[q]; }
  *(bf16x8*)(out + i) = o;
}

// ---- MFMA GEMM: C = act(A @ BT^T + bias), 128x128 tile, BK=32, blockIdx.z-select ----
// AMODE: 0 = A bf16 (global_load_lds, row stride lda); 1 = A f32 (reg-cvt, stride lda);
//        2 = gather concat(zr[prm[aoff+r]], zi[ord[aoff+r]])
// OSEL : 0 = C f32; 1 = C bf16.  BSPLIT: bias col<2048, bias2 col>=2048.
template <int ACT, int AMODE, int OSEL, int BSPLIT>
__global__ __launch_bounds__(256) void mgemm_k(ZP zp, const float* __restrict__ bias2,
                                               int M, int N, int K, int lda,
                                               const int* __restrict__ prmq,
                                               const int* __restrict__ ordq,
                                               const float* __restrict__ zr,
                                               const float* __restrict__ zi) {
  const int zsel = blockIdx.z;
  const void* A = zp.Az[zsel];
  const size_t aoff = zp.aoff[zsel];
  const __bf16* BT = zp.BTz[zsel];
  const float* bias = zp.biasz[zsel];
  void* Cc = zp.Cz[zsel];

  __shared__ __bf16 As[128][32];
  __shared__ __bf16 Bs[128][32];
  const int tid = threadIdx.x;
  const int wv = tid >> 6, ln = tid & 63;
  const int row0 = blockIdx.y * 128, col0 = blockIdx.x * 128;
  const int wr = wv >> 1, wc = wv & 1;
  const int lrow = ln & 15;
  const int kgrp = (ln >> 4) * 8;
  const int srow = tid >> 1;
  const int skh  = (tid & 1) * 16;

  f32x4 acc[4][4] = {};

  int sga = row0 + srow; sga = sga < M ? sga : M - 1;
  int pidx = 0, oidx = 0;
  if (AMODE == 2) {
    int po = (int)aoff + sga;
    pidx = prmq[po]; pidx = pidx < 0 ? 0 : (pidx > Bn - 1 ? Bn - 1 : pidx);
    oidx = ordq[po]; oidx = oidx < 0 ? 0 : (oidx > Bn - 1 ? Bn - 1 : oidx);
  }

  for (int k0 = 0; k0 < K; k0 += 32) {
#pragma unroll
    for (int it = 0; it < 2; ++it) {
      int byteoff = it * 4096 + wv * 1024 + ln * 16;
      int r = byteoff >> 6;
      int k8 = (byteoff >> 4) & 3;
      int gb = col0 + r; gb = gb < N ? gb : N - 1;
      gload_lds16(BT + (size_t)gb * K + k0 + k8 * 8, &Bs[0][0] + it * 2048 + wv * 512);
    }
    if (AMODE == 0) {
#pragma unroll
      for (int it = 0; it < 2; ++it) {
        int byteoff = it * 4096 + wv * 1024 + ln * 16;
        int r = byteoff >> 6;
        int k8 = (byteoff >> 4) & 3;
        int gr = row0 + r; gr = gr < M ? gr : M - 1;
        gload_lds16((const __bf16*)A + aoff + (size_t)gr * lda + k0 + k8 * 8,
                    &As[0][0] + it * 2048 + wv * 512);
      }
    } else {
      const int kk = k0 + skh;
      const float* Af;
      if (AMODE == 1) Af = (const float*)A + aoff + (size_t)sga * lda + kk;
      else Af = (kk < 512) ? (zr + (size_t)pidx * 512 + kk)
                           : (zi + (size_t)oidx * 512 + (kk - 512));
      f32x4 v0 = *(const f32x4*)(Af + 0);
      f32x4 v1 = *(const f32x4*)(Af + 4);
      f32x4 v2 = *(const f32x4*)(Af + 8);
      f32x4 v3 = *(const f32x4*)(Af + 12);
      bf16x8 alo, ahi;
#pragma unroll
      for (int q = 0; q < 4; ++q) { alo[q] = (__bf16)v0[q]; alo[q + 4] = (__bf16)v1[q]; }
#pragma unroll
      for (int q = 0; q < 4; ++q) { ahi[q] = (__bf16)v2[q]; ahi[q + 4] = (__bf16)v3[q]; }
      *(bf16x8*)&As[srow][skh]     = alo;
      *(bf16x8*)&As[srow][skh + 8] = ahi;
    }
    __syncthreads();

    s16x8 af[4], bfr[4];
#pragma unroll
    for (int i = 0; i < 4; ++i)
      af[i] = *(const s16x8*)&As[wr * 64 + i * 16 + lrow][kgrp];
#pragma unroll
    for (int j = 0; j < 4; ++j)
      bfr[j] = *(const s16x8*)&Bs[wc * 64 + j * 16 + lrow][kgrp];
#pragma unroll
    for (int i = 0; i < 4; ++i)
#pragma unroll
      for (int j = 0; j < 4; ++j)
        acc[i][j] = __builtin_amdgcn_mfma_f32_16x16x32_bf16(af[i], bfr[j], acc[i][j], 0, 0, 0);
    __syncthreads();
  }

  float bv[4]; int bcol[4];
#pragma unroll
  for (int j = 0; j < 4; ++j) {
    bcol[j] = col0 + wc * 64 + j * 16 + lrow;
    if (BSPLIT) bv[j] = (bcol[j] < 2048) ? bias[bcol[j]] : bias2[bcol[j] - 2048];
    else bv[j] = (bcol[j] < N) ? bias[bcol[j]] : 0.f;
  }
  const int rbase = row0 + wr * 64 + (ln >> 4) * 4;
#pragma unroll
  for (int i = 0; i < 4; ++i) {
#pragma unroll
    for (int rr = 0; rr < 4; ++rr) {
      int r = rbase + i * 16 + rr;
      if (r < M) {
#pragma unroll
        for (int j = 0; j < 4; ++j) {
          if (bcol[j] < N) {
            float v = acc[i][j][rr] + bv[j];
            if (ACT == 1) v = (v >= 0.f) ? v : 0.01f * v;
            if (OSEL == 0) ((float*)Cc)[(size_t)r * N + bcol[j]] = v;
            else ((__bf16*)Cc)[(size_t)r * N + bcol[j]] = (__bf16)v;
          }
        }
      }
    }
  }
}

__global__ __launch_bounds__(256) void gather512_k(const float* __restrict__ zE,
                                                   const int* __restrict__ labels,
                                                   float* __restrict__ dst) {
  int b = blockIdx.x * 4 + (threadIdx.x >> 6);
  int ln = threadIdx.x & 63;
  int g = labels[b]; g = g < 0 ? 0 : (g > 31 ? 31 : g);
#pragma unroll
  for (int q = 0; q < 8; ++q)
    dst[(size_t)b * 512 + ln * 8 + q] = zE[(size_t)g * 512 + ln * 8 + q];
}

__global__ __launch_bounds__(256) void threefry_s_k(const int* __restrict__ labels,
                                                    float* __restrict__ s) {
  int i = blockIdx.x * blockDim.x + threadIdx.x;
  if (i >= Bn) return;
  unsigned x0 = 0u, x1 = (unsigned)i;
  tf2x32(0u, 1234u, x0, x1);
  unsigned bits = x0 ^ x1;
  float u = __uint_as_float((bits >> 9) | 0x3f800000u) - 1.0f;
  u = fmaxf(u, 0.0f);
  s[i] = (float)labels[i] + u;
}

__global__ __launch_bounds__(256) void rank_k(const int* __restrict__ labels,
                                              const float* __restrict__ s,
                                              int* __restrict__ order,
                                              int* __restrict__ perm) {
  __shared__ unsigned char Ls[8192];
  __shared__ float Ss[8192];
  for (int j = threadIdx.x; j < 8192; j += 256) {
    Ls[j] = (unsigned char)labels[j];
    Ss[j] = s[j];
  }
  __syncthreads();
  int i = blockIdx.x * 32 + (threadIdx.x >> 3);
  int part = threadIdx.x & 7;
  int li = Ls[i];
  float si = Ss[i];
  int ro = 0, rp = 0;
  for (int j = part * 1024; j < (part + 1) * 1024; ++j) {
    int lj = Ls[j];
    float sj = Ss[j];
    ro += (lj < li || (lj == li && j < i)) ? 1 : 0;
    rp += (sj < si || (sj == si && j < i)) ? 1 : 0;
  }
#pragma unroll
  for (int d = 4; d; d >>= 1) {
    ro += __shfl_down(ro, d);
    rp += __shfl_down(rp, d);
  }
  if (part == 0) {
    order[ro] = i;
    perm[rp] = i;
  }
}

__global__ __launch_bounds__(256) void persample_k(const float* __restrict__ out,
                                                   float* __restrict__ costT,
                                                   float* __restrict__ psamp) {
  int b = blockIdx.x * 4 + (threadIdx.x >> 6);
  int ln = threadIdx.x & 63;
  float dlr = 0.f, dli = 0.f, nl = 0.f, nr = 0.f, ni = 0.f;
#pragma unroll
  for (int q = 0; q < 8; ++q) {
    size_t idx = (size_t)b * 512 + ln * 8 + q;
    float fl = out[ZL_OFF + idx];
    float fr = out[ZR_OFF + idx];
    float fi = out[ZI_OFF + idx];
    dlr += fl * fr; dli += fl * fi;
    nl += fl * fl;  nr += fr * fr;  ni += fi * fi;
  }
#pragma unroll
  for (int off = 32; off; off >>= 1) {
    dlr += __shfl_down(dlr, off);
    dli += __shfl_down(dli, off);
    nl  += __shfl_down(nl,  off);
    nr  += __shfl_down(nr,  off);
    ni  += __shfl_down(ni,  off);
  }
  if (ln == 0) {
    float snl = sqrtf(nl), snr = sqrtf(nr), sni = sqrtf(ni);
    float cost = 1.0f - dlr / (fmaxf(snl, 1e-5f) * fmaxf(snr, 1e-5f));
    float cp = dlr / (fmaxf(snl, 1e-8f) * fmaxf(snr, 1e-8f));
    float cn = dli / (fmaxf(snl, 1e-8f) * fmaxf(sni, 1e-8f));
    float d = 1.5f * (cn - cp);
    float ps = (d > 0.f) ? d + log1pf(expf(-d)) : log1pf(expf(d));
    float a = expf(-cost * 2.0f), sg = 1.f, T = 1.f;
    for (int t = 0; t < 50; ++t) {
      float q = a * T;
      float dl = 1.f / (q * sg);
      sg = 1.f / (dl * q);
      T = dl * q * sg;
    }
    costT[b] = cost * T;
    psamp[b] = ps;
  }
}

__global__ __launch_bounds__(256) void ot_reduce_k(const float* __restrict__ costT,
                                                   float* __restrict__ out) {
  __shared__ float red[256];
  float sum = 0.f;
  for (int i = threadIdx.x; i < Bn; i += 256) sum += costT[i];
  red[threadIdx.x] = sum;
  __syncthreads();
  for (int st = 128; st; st >>= 1) {
    if (threadIdx.x < st) red[threadIdx.x] += red[threadIdx.x + st];
    __syncthreads();
  }
  if (threadIdx.x == 0) out[OT_OFF] = red[0] / (float)Bn;
}

__global__ __launch_bounds__(256) void group_reduce_k(const int* __restrict__ labels,
                                                      const float* __restrict__ psamp,
                                                      float* __restrict__ gmean,
                                                      float* __restrict__ present) {
  int g = blockIdx.x;
  __shared__ float rs[256];
  __shared__ int rc[256];
  float s = 0.f; int c = 0;
  for (int i = threadIdx.x; i < Bn; i += 256)
    if (labels[i] == g) { s += psamp[i]; c++; }
  rs[threadIdx.x] = s; rc[threadIdx.x] = c;
  __syncthreads();
  for (int st = 128; st; st >>= 1) {
    if (threadIdx.x < st) { rs[threadIdx.x] += rs[threadIdx.x + st]; rc[threadIdx.x] += rc[threadIdx.x + st]; }
    __syncthreads();
  }
  if (threadIdx.x == 0) {
    gmean[g] = rc[0] > 0 ? rs[0] / (float)rc[0] : 0.f;
    present[g] = rc[0] > 0 ? 1.f : 0.f;
  }
}

__global__ void contra_final_k(const float* __restrict__ gmean,
                               const float* __restrict__ present,
                               float* __restrict__ out) {
  if (threadIdx.x == 0) {
    float s = 0.f, p = 0.f;
    for (int g = 0; g < 32; ++g) { s += gmean[g]; p += present[g]; }
    out[CT_OFF] = s / p;
  }
}

__global__ __launch_bounds__(128) void xori_k(const float* __restrict__ x,
                                              const int* __restrict__ order,
                                              float* __restrict__ out) {
  int j = blockIdx.x, t = threadIdx.x;
  int o = order[j]; o = o < 0 ? 0 : (o > Bn - 1 ? Bn - 1 : o);
#pragma unroll
  for (int q = 0; q < 8; ++q)
    out[XO_OFF + (size_t)j * 1024 + t * 8 + q] = x[(size_t)o * 1024 + t * 8 + q];
}

__global__ __launch_bounds__(256) void bnacc_k(const __bf16* __restrict__ h,
                                               float* __restrict__ sum,
                                               float* __restrict__ sum2,
                                               int slotbase) {
  int colbase = blockIdx.x * 64;
  int rowbase = blockIdx.y * 256;
  int lc = threadIdx.x & 63, rg = threadIdx.x >> 6;
  float s = 0.f, s2 = 0.f;
  for (int r = rowbase + rg; r < rowbase + 256; r += 4) {
    float v = (float)h[(size_t)r * 2048 + colbase + lc];
    s += v; s2 += v * v;
  }
  __shared__ float sh[4][64], sh2[4][64];
  sh[rg][lc] = s; sh2[rg][lc] = s2;
  __syncthreads();
  if (rg == 0) {
    s  = sh[0][lc] + sh[1][lc] + sh[2][lc] + sh[3][lc];
    s2 = sh2[0][lc] + sh2[1][lc] + sh2[2][lc] + sh2[3][lc];
    int slot = slotbase + blockIdx.y;
    sum[(size_t)slot * 2048 + colbase + lc]  = s;
    sum2[(size_t)slot * 2048 + colbase + lc] = s2;
  }
}

__global__ __launch_bounds__(256) void bnfinal_k(const float* __restrict__ sumA,
                                                 const float* __restrict__ sum2A,
                                                 const float* __restrict__ gamma,
                                                 const float* __restrict__ beta,
                                                 float* __restrict__ scale,
                                                 float* __restrict__ shift) {
  int c = blockIdx.x * 256 + threadIdx.x;
  float s = 0.f, s2 = 0.f;
  for (int q = 0; q < 32; ++q) { s += sumA[(size_t)q * 2048 + c]; s2 += sum2A[(size_t)q * 2048 + c]; }
  float mu = s / (float)Bn;
  float var = s2 / (float)Bn - mu * mu;
  float sc = gamma[c] / sqrtf(var + 1e-5f);
  scale[c] = sc;
  shift[c] = beta[c] - mu * sc;
}

__global__ __launch_bounds__(256) void bnapply_k(__bf16* __restrict__ h,
                                                 const float* __restrict__ scale,
                                                 const float* __restrict__ shift) {
  size_t i = (size_t)blockIdx.x * 256 + threadIdx.x;
#pragma unroll
  for (int q = 0; q < 8; ++q) {
    size_t e = i * 8 + q;
    int col = (int)(e & 2047);
    float f = (float)h[e] * scale[col] + shift[col];
    f = (f >= 0.f) ? f : 0.01f * f;
    h[e] = (__bf16)f;
  }
}

__global__ void marker_k(float* __restrict__ p, float v) {
  if (threadIdx.x == 0) *p = v;
}

// ==================================================================================
extern "C" void kernel_launch(void* const* d_in, const int* in_sizes, int n_in,
                              void* d_out, int out_size, void* d_ws, size_t ws_size,
                              hipStream_t stream) {
  const float* x    = (const float*)d_in[0];
  const int*  labels = (const int*)d_in[1];
  const float* Wr1 = (const float*)d_in[2];  const float* br1 = (const float*)d_in[3];
  const float* Wr2 = (const float*)d_in[4];  const float* br2 = (const float*)d_in[5];
  const float* Wi1 = (const float*)d_in[6];  const float* bi1 = (const float*)d_in[7];
  const float* Wi2 = (const float*)d_in[8];  const float* bi2 = (const float*)d_in[9];
  const float* E   = (const float*)d_in[10];
  const float* Wd1 = (const float*)d_in[11]; const float* bd1 = (const float*)d_in[12];
  const float* Wd2 = (const float*)d_in[13]; const float* bd2 = (const float*)d_in[14];
  const float* Wc1 = (const float*)d_in[15]; const float* bc1 = (const float*)d_in[16];
  const float* bng = (const float*)d_in[17]; const float* bnb = (const float*)d_in[18];
  const float* Wc2 = (const float*)d_in[19]; const float* bc2 = (const float*)d_in[20];

  float* out = (float*)d_out;
  dim3 b256(256);
  const int* ni = nullptr;
  const float* nf = nullptr;

  if (ws_size < (1u << 20)) {
    marker_k<<<dim3(1), dim3(64), 0, stream>>>(out + XR_OFF, 110.f);
    return;
  }

  char* wsb = (char*)d_ws;
  float* sval   = (float*)(wsb);
  float* costT  = (float*)(wsb + 32768);
  float* psamp  = (float*)(wsb + 65536);
  int*   ordr   = (int*)  (wsb + 98304);
  int*   prm    = (int*)  (wsb + 131072);
  float* gmean  = (float*)(wsb + 164096);
  float* present= (float*)(wsb + 164224);
  float* bnscale= (float*)(wsb + 164352);
  float* bnshift= (float*)(wsb + 172544);
  float* bnsum  = (float*)(wsb + 180736);   // 32 slots x 2048 f32 = 256 KB
  float* bnsum2 = (float*)(wsb + 442880);   // 256 KB
  __bf16* hE    = (__bf16*)(wsb + 705024);  // 32x2048 bf16 = 128 KB
  float*  zE    = (float*)(wsb + 836096);   // 32x512 f32 = 64 KB

  // ---- scratch layouts (f32 slot offsets into dead regions) ----
  // Phase E (xori zone): TAB[0,2M) TB2[2M,3M) xch[3M,4M) hLR[4M,8M) (1-slot CT spill, rewritten)
  __bf16* TAB  = (__bf16*)(out + SB_OFF);
  __bf16* TB2  = (__bf16*)(out + SB_OFF + 2097152);
  __bf16* xch  = (__bf16*)(out + SB_OFF + 3145728);
  __bf16* hLR  = (__bf16*)(out + SB_OFF + 4194304);
  // Phase C (classifier, BEFORE decoder): TAc/TBc in xori zone; hcAll = XR region
  __bf16* TAc   = (__bf16*)(out + SB_OFF);             // [2048][512]  = 0.5M slots
  __bf16* TBc   = (__bf16*)(out + SB_OFF + 524288);    // [32][2048]   = 32K slots
  __bf16* hcAll = (__bf16*)(out + XR_OFF);             // [8192][2048] = 8M slots (dead XR)
  // Phase D (decoder): TAd[0,1M) TBd[1M,2M) hb0[2M,4M) hb1[4M,6M) in xori zone
  __bf16* TAd  = (__bf16*)(out + SB_OFF);
  __bf16* TBd  = (__bf16*)(out + SB_OFF + 1048576);
  __bf16* hb0  = (__bf16*)(out + SB_OFF + 2097152);
  __bf16* hb1  = (__bf16*)(out + SB_OFF + 4194304);

  auto zp1 = [](const void* A, size_t aoff, const __bf16* BT, const float* b, void* C) {
    ZP z; z.Az[0] = z.Az[1] = A; z.aoff[0] = z.aoff[1] = aoff;
    z.BTz[0] = z.BTz[1] = BT; z.biasz[0] = z.biasz[1] = b; z.Cz[0] = z.Cz[1] = C; return z;
  };
  auto zp2 = [](const void* A0, const void* A1, size_t o0, size_t o1,
                const __bf16* B0, const __bf16* B1, const float* b0, const float* b1,
                void* C0, void* C1) {
    ZP z; z.Az[0] = A0; z.Az[1] = A1; z.aoff[0] = o0; z.aoff[1] = o1;
    z.BTz[0] = B0; z.BTz[1] = B1; z.biasz[0] = b0; z.biasz[1] = b1;
    z.Cz[0] = C0; z.Cz[1] = C1; return z;
  };

  // ---- merged encoders ----
  transpose_k<<<dim3(64, 32), b256, 0, stream>>>(Wr1, TAB, 1024, 2048);
  transpose_k<<<dim3(64, 32), b256, 0, stream>>>(Wi1, TAB + 2097152, 1024, 2048);
  transpose_k<<<dim3(16, 64), b256, 0, stream>>>(Wr2, TB2, 2048, 512);
  transpose_k<<<dim3(16, 64), b256, 0, stream>>>(Wi2, TB2 + 1048576, 2048, 512);
  for (int mc = 0; mc < 4; ++mc) {
    cvt_k<<<dim3(1024), b256, 0, stream>>>(x + (size_t)mc * 2097152, xch);
    mgemm_k<1,0,1,1><<<dim3(32, 16, 1), b256, 0, stream>>>(
        zp1(xch, 0, TAB, br1, hLR), bi1, 2048, 4096, 1024, 1024, ni, ni, nf, nf);
    mgemm_k<0,0,0,0><<<dim3(4, 16, 2), b256, 0, stream>>>(
        zp2(hLR, hLR, 0, 2048, TB2, TB2 + 1048576, br2, bi2,
            out + ZR_OFF + (size_t)mc * 1048576, out + ZI_OFF + (size_t)mc * 1048576),
        nf, 2048, 512, 2048, 4096, ni, ni, nf, nf);
  }
  // ---- label encoder + gather ----
  mgemm_k<1,1,1,0><<<dim3(16, 1, 1), b256, 0, stream>>>(
      zp1(E, 0, TAB, br1, hE), nf, 32, 2048, 1024, 1024, ni, ni, nf, nf);
  mgemm_k<0,0,0,0><<<dim3(4, 1, 1), b256, 0, stream>>>(
      zp1(hE, 0, TB2, br2, zE), nf, 32, 512, 2048, 2048, ni, ni, nf, nf);
  gather512_k<<<dim3(2048), b256, 0, stream>>>(zE, labels, out + ZL_OFF);

  // ---- permutations + per-sample losses ----
  threefry_s_k<<<dim3(32), b256, 0, stream>>>(labels, sval);
  rank_k<<<dim3(256), b256, 0, stream>>>(labels, sval, ordr, prm);
  persample_k<<<dim3(2048), b256, 0, stream>>>(out, costT, psamp);
  group_reduce_k<<<dim3(32), b256, 0, stream>>>(labels, psamp, gmean, present);

  // ---- classifier FIRST (hcAll in dead XR region; single L1 pass) ----
  transpose_k<<<dim3(64, 16), b256, 0, stream>>>(Wc1, TAc, 512, 2048);
  transpose_k<<<dim3(1, 64), b256, 0, stream>>>(Wc2, TBc, 2048, 32);
  mgemm_k<0,1,1,0><<<dim3(16, 64, 1), b256, 0, stream>>>(
      zp1(out + ZR_OFF, 0, TAc, bc1, hcAll), nf, 8192, 2048, 512, 512, ni, ni, nf, nf);
  bnacc_k<<<dim3(32, 32), b256, 0, stream>>>(hcAll, bnsum, bnsum2, 0);
  bnfinal_k<<<dim3(8), b256, 0, stream>>>(bnsum, bnsum2, bng, bnb, bnscale, bnshift);
  bnapply_k<<<dim3(8192), b256, 0, stream>>>(hcAll, bnscale, bnshift);
  mgemm_k<0,0,0,0><<<dim3(1, 64, 1), b256, 0, stream>>>(
      zp1(hcAll, 0, TBc, bc2, out + LG_OFF), nf, 8192, 32, 2048, 2048, ni, ni, nf, nf);

  // ---- decoder (L1 z-paired; overwrites XR) ----
  transpose_k<<<dim3(64, 32), b256, 0, stream>>>(Wd1, TAd, 1024, 2048);
  transpose_k<<<dim3(32, 64), b256, 0, stream>>>(Wd2, TBd, 2048, 1024);
  for (int mp = 0; mp < 2; ++mp) {
    int c0 = 2 * mp, c1 = 2 * mp + 1;
    mgemm_k<1,2,1,0><<<dim3(16, 16, 2), b256, 0, stream>>>(
        zp2(nullptr, nullptr, (size_t)c0 * 2048, (size_t)c1 * 2048,
            TAd, TAd, bd1, bd1, hb0, hb1),
        nf, 2048, 2048, 1024, 0, prm, ordr, out + ZR_OFF, out + ZI_OFF);
    mgemm_k<0,0,0,0><<<dim3(8, 16, 2), b256, 0, stream>>>(
        zp2(hb0, hb1, 0, 0, TBd, TBd, bd2, bd2,
            out + XR_OFF + (size_t)c0 * 2097152, out + XR_OFF + (size_t)c1 * 2097152),
        nf, 2048, 1024, 2048, 2048, ni, ni, nf, nf);
  }

  // ---- scalar finals, x_ori LAST ----
  ot_reduce_k<<<dim3(1), b256, 0, stream>>>(costT, out);
  contra_final_k<<<dim3(1), dim3(64), 0, stream>>>(gmean, present, out);
  xori_k<<<dim3(8192), dim3(128), 0, stream>>>(x, ordr, out);

  (void)in_sizes; (void)n_in; (void)out_size;
}

// Round 23
// 918.734 us; speedup vs baseline: 10.6547x; 1.1377x over previous
//
#include <hip/hip_runtime.h>

typedef short  s16x8 __attribute__((ext_vector_type(8)));
typedef __bf16 bf16x8 __attribute__((ext_vector_type(8)));
typedef float  f32x4 __attribute__((ext_vector_type(4)));

static constexpr int Bn = 8192;
static constexpr size_t XR_OFF = 0;
static constexpr size_t ZL_OFF = 8388608;
static constexpr size_t ZR_OFF = 12582912;
static constexpr size_t ZI_OFF = 16777216;
static constexpr size_t OT_OFF = 20971520;
static constexpr size_t XO_OFF = 20971521;
static constexpr size_t CT_OFF = 29360129;
static constexpr size_t LG_OFF = 29360130;
static constexpr size_t SB_OFF = 20971522;

struct ZP {
  const void* Az[2];
  size_t aoff[2];
  const __bf16* BTz[2];
  const float* biasz[2];
  void* Cz[2];
};

__device__ __forceinline__ void gload_lds16(const void* g, void* l) {
  __builtin_amdgcn_global_load_lds((const __attribute__((address_space(1))) void*)g,
                                   (__attribute__((address_space(3))) void*)l, 16, 0, 0);
}

__device__ __forceinline__ void tf2x32(unsigned k0, unsigned k1, unsigned& x0, unsigned& x1) {
  const unsigned ks[3] = {k0, k1, k0 ^ k1 ^ 0x1BD11BDAu};
  x0 += ks[0]; x1 += ks[1];
  const int R1r[4] = {13, 15, 26, 6}, R2r[4] = {17, 29, 16, 24};
#pragma unroll
  for (int g = 0; g < 5; ++g) {
    const int* rr = (g & 1) ? R2r : R1r;
#pragma unroll
    for (int q = 0; q < 4; ++q) {
      x0 += x1;
      x1 = (x1 << rr[q]) | (x1 >> (32 - rr[q]));
      x1 ^= x0;
    }
    x0 += ks[(g + 1) % 3];
    x1 += ks[(g + 2) % 3] + (unsigned)(g + 1);
  }
}

__global__ __launch_bounds__(256) void transpose_k(const float* __restrict__ in,
                                                   __bf16* __restrict__ out,
                                                   int R, int C) {
  __shared__ float t[32][33];
  int c0 = blockIdx.x * 32, r0 = blockIdx.y * 32;
  int lc = threadIdx.x & 31, lr = threadIdx.x >> 5;
#pragma unroll
  for (int i = 0; i < 4; ++i) {
    int r = lr + i * 8;
    t[r][lc] = in[(size_t)(r0 + r) * C + c0 + lc];
  }
  __syncthreads();
#pragma unroll
  for (int i = 0; i < 4; ++i) {
    int cc = lr + i * 8;
    out[(size_t)(c0 + cc) * R + r0 + lc] = (__bf16)t[lc][cc];
  }
}

__global__ __launch_bounds__(256) void cvt_k(const float* __restrict__ in,
                                             __bf16* __restrict__ out) {
  size_t i = ((size_t)blockIdx.x * 256 + threadIdx.x) * 8;
  f32x4 v0 = *(const f32x4*)(in + i);
  f32x4 v1 = *(const f32x4*)(in + i + 4);
  bf16x8 o;
#pragma unroll
  for (int q = 0; q < 4; ++q) { o[q] = (__bf16)v0[q]; o[q + 4] = (__bf16)v1[q]; }
  *(bf16x8*)(out + i) = o;
}

// ---- MFMA GEMM: C = act(A @ BT^T + bias), 128x128 tile, BK=32, blockIdx.z-select ----
// AMODE: 0 = A bf16 (global_load_lds, row stride lda, +elem offset aoff);
//        1 = A f32 (reg-cvt, stride lda); 2 = gather concat(zr[prm[aoff+r]], zi[ord[aoff+r]])
// OSEL : 0 = C f32; 1 = C bf16.  BSPLIT: bias col<2048, bias2 col>=2048.
template <int ACT, int AMODE, int OSEL, int BSPLIT>
__global__ __launch_bounds__(256) void mgemm_k(ZP zp, const float* __restrict__ bias2,
                                               int M, int N, int K, int lda,
                                               const int* __restrict__ prmq,
                                               const int* __restrict__ ordq,
                                               const float* __restrict__ zr,
                                               const float* __restrict__ zi) {
  const int zsel = blockIdx.z;
  const void* A = zp.Az[zsel];
  const size_t aoff = zp.aoff[zsel];
  const __bf16* BT = zp.BTz[zsel];
  const float* bias = zp.biasz[zsel];
  void* Cc = zp.Cz[zsel];

  __shared__ __bf16 As[128][32];
  __shared__ __bf16 Bs[128][32];
  const int tid = threadIdx.x;
  const int wv = tid >> 6, ln = tid & 63;
  const int row0 = blockIdx.y * 128, col0 = blockIdx.x * 128;
  const int wr = wv >> 1, wc = wv & 1;
  const int lrow = ln & 15;
  const int kgrp = (ln >> 4) * 8;
  const int srow = tid >> 1;
  const int skh  = (tid & 1) * 16;

  f32x4 acc[4][4] = {};

  int sga = row0 + srow; sga = sga < M ? sga : M - 1;
  int pidx = 0, oidx = 0;
  if (AMODE == 2) {
    int po = (int)aoff + sga;
    pidx = prmq[po]; pidx = pidx < 0 ? 0 : (pidx > Bn - 1 ? Bn - 1 : pidx);
    oidx = ordq[po]; oidx = oidx < 0 ? 0 : (oidx > Bn - 1 ? Bn - 1 : oidx);
  }

  for (int k0 = 0; k0 < K; k0 += 32) {
#pragma unroll
    for (int it = 0; it < 2; ++it) {
      int byteoff = it * 4096 + wv * 1024 + ln * 16;
      int r = byteoff >> 6;
      int k8 = (byteoff >> 4) & 3;
      int gb = col0 + r; gb = gb < N ? gb : N - 1;
      gload_lds16(BT + (size_t)gb * K + k0 + k8 * 8, &Bs[0][0] + it * 2048 + wv * 512);
    }
    if (AMODE == 0) {
#pragma unroll
      for (int it = 0; it < 2; ++it) {
        int byteoff = it * 4096 + wv * 1024 + ln * 16;
        int r = byteoff >> 6;
        int k8 = (byteoff >> 4) & 3;
        int gr = row0 + r; gr = gr < M ? gr : M - 1;
        gload_lds16((const __bf16*)A + aoff + (size_t)gr * lda + k0 + k8 * 8,
                    &As[0][0] + it * 2048 + wv * 512);
      }
    } else {
      const int kk = k0 + skh;
      const float* Af;
      if (AMODE == 1) Af = (const float*)A + aoff + (size_t)sga * lda + kk;
      else Af = (kk < 512) ? (zr + (size_t)pidx * 512 + kk)
                           : (zi + (size_t)oidx * 512 + (kk - 512));
      f32x4 v0 = *(const f32x4*)(Af + 0);
      f32x4 v1 = *(const f32x4*)(Af + 4);
      f32x4 v2 = *(const f32x4*)(Af + 8);
      f32x4 v3 = *(const f32x4*)(Af + 12);
      bf16x8 alo, ahi;
#pragma unroll
      for (int q = 0; q < 4; ++q) { alo[q] = (__bf16)v0[q]; alo[q + 4] = (__bf16)v1[q]; }
#pragma unroll
      for (int q = 0; q < 4; ++q) { ahi[q] = (__bf16)v2[q]; ahi[q + 4] = (__bf16)v3[q]; }
      *(bf16x8*)&As[srow][skh]     = alo;
      *(bf16x8*)&As[srow][skh + 8] = ahi;
    }
    __syncthreads();

    s16x8 af[4], bfr[4];
#pragma unroll
    for (int i = 0; i < 4; ++i)
      af[i] = *(const s16x8*)&As[wr * 64 + i * 16 + lrow][kgrp];
#pragma unroll
    for (int j = 0; j < 4; ++j)
      bfr[j] = *(const s16x8*)&Bs[wc * 64 + j * 16 + lrow][kgrp];
#pragma unroll
    for (int i = 0; i < 4; ++i)
#pragma unroll
      for (int j = 0; j < 4; ++j)
        acc[i][j] = __builtin_amdgcn_mfma_f32_16x16x32_bf16(af[i], bfr[j], acc[i][j], 0, 0, 0);
    __syncthreads();
  }

  float bv[4]; int bcol[4];
#pragma unroll
  for (int j = 0; j < 4; ++j) {
    bcol[j] = col0 + wc * 64 + j * 16 + lrow;
    if (BSPLIT) bv[j] = (bcol[j] < 2048) ? bias[bcol[j]] : bias2[bcol[j] - 2048];
    else bv[j] = (bcol[j] < N) ? bias[bcol[j]] : 0.f;
  }
  const int rbase = row0 + wr * 64 + (ln >> 4) * 4;
#pragma unroll
  for (int i = 0; i < 4; ++i) {
#pragma unroll
    for (int rr = 0; rr < 4; ++rr) {
      int r = rbase + i * 16 + rr;
      if (r < M) {
#pragma unroll
        for (int j = 0; j < 4; ++j) {
          if (bcol[j] < N) {
            float v = acc[i][j][rr] + bv[j];
            if (ACT == 1) v = (v >= 0.f) ? v : 0.01f * v;
            if (OSEL == 0) ((float*)Cc)[(size_t)r * N + bcol[j]] = v;
            else ((__bf16*)Cc)[(size_t)r * N + bcol[j]] = (__bf16)v;
          }
        }
      }
    }
  }
}

__global__ __launch_bounds__(256) void gather512_k(const float* __restrict__ zE,
                                                   const int* __restrict__ labels,
                                                   float* __restrict__ dst) {
  int b = blockIdx.x * 4 + (threadIdx.x >> 6);
  int ln = threadIdx.x & 63;
  int g = labels[b]; g = g < 0 ? 0 : (g > 31 ? 31 : g);
#pragma unroll
  for (int q = 0; q < 8; ++q)
    dst[(size_t)b * 512 + ln * 8 + q] = zE[(size_t)g * 512 + ln * 8 + q];
}

__global__ __launch_bounds__(256) void threefry_s_k(const int* __restrict__ labels,
                                                    float* __restrict__ s) {
  int i = blockIdx.x * blockDim.x + threadIdx.x;
  if (i >= Bn) return;
  unsigned x0 = 0u, x1 = (unsigned)i;
  tf2x32(0u, 1234u, x0, x1);
  unsigned bits = x0 ^ x1;
  float u = __uint_as_float((bits >> 9) | 0x3f800000u) - 1.0f;
  u = fmaxf(u, 0.0f);
  s[i] = (float)labels[i] + u;
}

__global__ __launch_bounds__(256) void rank_k(const int* __restrict__ labels,
                                              const float* __restrict__ s,
                                              int* __restrict__ order,
                                              int* __restrict__ perm) {
  __shared__ unsigned char Ls[8192];
  __shared__ float Ss[8192];
  for (int j = threadIdx.x; j < 8192; j += 256) {
    Ls[j] = (unsigned char)labels[j];
    Ss[j] = s[j];
  }
  __syncthreads();
  int i = blockIdx.x * 32 + (threadIdx.x >> 3);
  int part = threadIdx.x & 7;
  int li = Ls[i];
  float si = Ss[i];
  int ro = 0, rp = 0;
  for (int j = part * 1024; j < (part + 1) * 1024; ++j) {
    int lj = Ls[j];
    float sj = Ss[j];
    ro += (lj < li || (lj == li && j < i)) ? 1 : 0;
    rp += (sj < si || (sj == si && j < i)) ? 1 : 0;
  }
#pragma unroll
  for (int d = 4; d; d >>= 1) {
    ro += __shfl_down(ro, d);
    rp += __shfl_down(rp, d);
  }
  if (part == 0) {
    order[ro] = i;
    perm[rp] = i;
  }
}

// ---- per-sample losses; z_label read as zE[labels[b]] directly ----
__global__ __launch_bounds__(256) void persample_k(const float* __restrict__ out,
                                                   const float* __restrict__ zE,
                                                   const int* __restrict__ labels,
                                                   float* __restrict__ costT,
                                                   float* __restrict__ psamp) {
  int b = blockIdx.x * 4 + (threadIdx.x >> 6);
  int ln = threadIdx.x & 63;
  int g = labels[b]; g = g < 0 ? 0 : (g > 31 ? 31 : g);
  float dlr = 0.f, dli = 0.f, nl = 0.f, nr = 0.f, ni = 0.f;
#pragma unroll
  for (int q = 0; q < 8; ++q) {
    size_t idx = (size_t)b * 512 + ln * 8 + q;
    float fl = zE[(size_t)g * 512 + ln * 8 + q];
    float fr = out[ZR_OFF + idx];
    float fi = out[ZI_OFF + idx];
    dlr += fl * fr; dli += fl * fi;
    nl += fl * fl;  nr += fr * fr;  ni += fi * fi;
  }
#pragma unroll
  for (int off = 32; off; off >>= 1) {
    dlr += __shfl_down(dlr, off);
    dli += __shfl_down(dli, off);
    nl  += __shfl_down(nl,  off);
    nr  += __shfl_down(nr,  off);
    ni  += __shfl_down(ni,  off);
  }
  if (ln == 0) {
    float snl = sqrtf(nl), snr = sqrtf(nr), sni = sqrtf(ni);
    float cost = 1.0f - dlr / (fmaxf(snl, 1e-5f) * fmaxf(snr, 1e-5f));
    float cp = dlr / (fmaxf(snl, 1e-8f) * fmaxf(snr, 1e-8f));
    float cn = dli / (fmaxf(snl, 1e-8f) * fmaxf(sni, 1e-8f));
    float d = 1.5f * (cn - cp);
    float ps = (d > 0.f) ? d + log1pf(expf(-d)) : log1pf(expf(d));
    float a = expf(-cost * 2.0f), sg = 1.f, T = 1.f;
    for (int t = 0; t < 50; ++t) {
      float q = a * T;
      float dl = 1.f / (q * sg);
      sg = 1.f / (dl * q);
      T = dl * q * sg;
    }
    costT[b] = cost * T;
    psamp[b] = ps;
  }
}

__global__ __launch_bounds__(256) void ot_reduce_k(const float* __restrict__ costT,
                                                   float* __restrict__ out) {
  __shared__ float red[256];
  float sum = 0.f;
  for (int i = threadIdx.x; i < Bn; i += 256) sum += costT[i];
  red[threadIdx.x] = sum;
  __syncthreads();
  for (int st = 128; st; st >>= 1) {
    if (threadIdx.x < st) red[threadIdx.x] += red[threadIdx.x + st];
    __syncthreads();
  }
  if (threadIdx.x == 0) out[OT_OFF] = red[0] / (float)Bn;
}

__global__ __launch_bounds__(256) void group_reduce_k(const int* __restrict__ labels,
                                                      const float* __restrict__ psamp,
                                                      float* __restrict__ gmean,
                                                      float* __restrict__ present) {
  int g = blockIdx.x;
  __shared__ float rs[256];
  __shared__ int rc[256];
  float s = 0.f; int c = 0;
  for (int i = threadIdx.x; i < Bn; i += 256)
    if (labels[i] == g) { s += psamp[i]; c++; }
  rs[threadIdx.x] = s; rc[threadIdx.x] = c;
  __syncthreads();
  for (int st = 128; st; st >>= 1) {
    if (threadIdx.x < st) { rs[threadIdx.x] += rs[threadIdx.x + st]; rc[threadIdx.x] += rc[threadIdx.x + st]; }
    __syncthreads();
  }
  if (threadIdx.x == 0) {
    gmean[g] = rc[0] > 0 ? rs[0] / (float)rc[0] : 0.f;
    present[g] = rc[0] > 0 ? 1.f : 0.f;
  }
}

__global__ void contra_final_k(const float* __restrict__ gmean,
                               const float* __restrict__ present,
                               float* __restrict__ out) {
  if (threadIdx.x == 0) {
    float s = 0.f, p = 0.f;
    for (int g = 0; g < 32; ++g) { s += gmean[g]; p += present[g]; }
    out[CT_OFF] = s / p;
  }
}

__global__ __launch_bounds__(128) void xori_k(const float* __restrict__ x,
                                              const int* __restrict__ order,
                                              float* __restrict__ out) {
  int j = blockIdx.x, t = threadIdx.x;
  int o = order[j]; o = o < 0 ? 0 : (o > Bn - 1 ? Bn - 1 : o);
#pragma unroll
  for (int q = 0; q < 8; ++q)
    out[XO_OFF + (size_t)j * 1024 + t * 8 + q] = x[(size_t)o * 1024 + t * 8 + q];
}

__global__ __launch_bounds__(256) void bnacc_k(const __bf16* __restrict__ h,
                                               float* __restrict__ sum,
                                               float* __restrict__ sum2,
                                               int slotbase) {
  int colbase = blockIdx.x * 64;
  int rowbase = blockIdx.y * 256;
  int lc = threadIdx.x & 63, rg = threadIdx.x >> 6;
  float s = 0.f, s2 = 0.f;
  for (int r = rowbase + rg; r < rowbase + 256; r += 4) {
    float v = (float)h[(size_t)r * 2048 + colbase + lc];
    s += v; s2 += v * v;
  }
  __shared__ float sh[4][64], sh2[4][64];
  sh[rg][lc] = s; sh2[rg][lc] = s2;
  __syncthreads();
  if (rg == 0) {
    s  = sh[0][lc] + sh[1][lc] + sh[2][lc] + sh[3][lc];
    s2 = sh2[0][lc] + sh2[1][lc] + sh2[2][lc] + sh2[3][lc];
    int slot = slotbase + blockIdx.y;
    sum[(size_t)slot * 2048 + colbase + lc]  = s;
    sum2[(size_t)slot * 2048 + colbase + lc] = s2;
  }
}

__global__ __launch_bounds__(256) void bnfinal_k(const float* __restrict__ sumA,
                                                 const float* __restrict__ sum2A,
                                                 const float* __restrict__ gamma,
                                                 const float* __restrict__ beta,
                                                 float* __restrict__ scale,
                                                 float* __restrict__ shift) {
  int c = blockIdx.x * 256 + threadIdx.x;
  float s = 0.f, s2 = 0.f;
  for (int q = 0; q < 32; ++q) { s += sumA[(size_t)q * 2048 + c]; s2 += sum2A[(size_t)q * 2048 + c]; }
  float mu = s / (float)Bn;
  float var = s2 / (float)Bn - mu * mu;
  float sc = gamma[c] / sqrtf(var + 1e-5f);
  scale[c] = sc;
  shift[c] = beta[c] - mu * sc;
}

__global__ __launch_bounds__(256) void bnapply_k(__bf16* __restrict__ h,
                                                 const float* __restrict__ scale,
                                                 const float* __restrict__ shift) {
  size_t i = (size_t)blockIdx.x * 256 + threadIdx.x;
#pragma unroll
  for (int q = 0; q < 8; ++q) {
    size_t e = i * 8 + q;
    int col = (int)(e & 2047);
    float f = (float)h[e] * scale[col] + shift[col];
    f = (f >= 0.f) ? f : 0.01f * f;
    h[e] = (__bf16)f;
  }
}

__global__ void marker_k(float* __restrict__ p, float v) {
  if (threadIdx.x == 0) *p = v;
}

// ==================================================================================
extern "C" void kernel_launch(void* const* d_in, const int* in_sizes, int n_in,
                              void* d_out, int out_size, void* d_ws, size_t ws_size,
                              hipStream_t stream) {
  const float* x    = (const float*)d_in[0];
  const int*  labels = (const int*)d_in[1];
  const float* Wr1 = (const float*)d_in[2];  const float* br1 = (const float*)d_in[3];
  const float* Wr2 = (const float*)d_in[4];  const float* br2 = (const float*)d_in[5];
  const float* Wi1 = (const float*)d_in[6];  const float* bi1 = (const float*)d_in[7];
  const float* Wi2 = (const float*)d_in[8];  const float* bi2 = (const float*)d_in[9];
  const float* E   = (const float*)d_in[10];
  const float* Wd1 = (const float*)d_in[11]; const float* bd1 = (const float*)d_in[12];
  const float* Wd2 = (const float*)d_in[13]; const float* bd2 = (const float*)d_in[14];
  const float* Wc1 = (const float*)d_in[15]; const float* bc1 = (const float*)d_in[16];
  const float* bng = (const float*)d_in[17]; const float* bnb = (const float*)d_in[18];
  const float* Wc2 = (const float*)d_in[19]; const float* bc2 = (const float*)d_in[20];

  float* out = (float*)d_out;
  dim3 b256(256);
  const int* ni = nullptr;
  const float* nf = nullptr;

  if (ws_size < (1u << 20)) {
    marker_k<<<dim3(1), dim3(64), 0, stream>>>(out + XR_OFF, 110.f);
    return;
  }

  char* wsb = (char*)d_ws;
  float* sval   = (float*)(wsb);
  float* costT  = (float*)(wsb + 32768);
  float* psamp  = (float*)(wsb + 65536);
  int*   ordr   = (int*)  (wsb + 98304);
  int*   prm    = (int*)  (wsb + 131072);
  float* gmean  = (float*)(wsb + 164096);
  float* present= (float*)(wsb + 164224);
  float* bnscale= (float*)(wsb + 164352);
  float* bnshift= (float*)(wsb + 172544);
  float* bnsum  = (float*)(wsb + 180736);   // 32 slots x 2048 f32 = 256 KB
  float* bnsum2 = (float*)(wsb + 442880);   // 256 KB
  __bf16* hE    = (__bf16*)(wsb + 705024);  // 32x2048 bf16
  float*  zE    = (float*)(wsb + 836096);   // 32x512 f32

  // ---- scratch layouts ----
  // Phase E (2 chunks of 4096 rows):
  //   hLR = XR region [0,8M)  ([4096][4096] bf16)
  //   xori zone: TAB[0,2M) TB2[2M,3M) xch[3M,5M) ([4096][1024] bf16)
  __bf16* hLR  = (__bf16*)(out + XR_OFF);
  __bf16* TAB  = (__bf16*)(out + SB_OFF);
  __bf16* TB2  = (__bf16*)(out + SB_OFF + 2097152);
  __bf16* xch  = (__bf16*)(out + SB_OFF + 3145728);
  // Phase C: TAc[0,0.5M) TBc[0.5M,+32K) in xori zone; hcAll = XR region
  __bf16* TAc   = (__bf16*)(out + SB_OFF);
  __bf16* TBc   = (__bf16*)(out + SB_OFF + 524288);
  __bf16* hcAll = (__bf16*)(out + XR_OFF);
  // Phase D (2 chunks of 4096): TAd[0,1M) TBd[1M,2M) hb[2M,6M) ([4096][2048] bf16)
  __bf16* TAd  = (__bf16*)(out + SB_OFF);
  __bf16* TBd  = (__bf16*)(out + SB_OFF + 1048576);
  __bf16* hb   = (__bf16*)(out + SB_OFF + 2097152);

  auto zp1 = [](const void* A, size_t aoff, const __bf16* BT, const float* b, void* C) {
    ZP z; z.Az[0] = z.Az[1] = A; z.aoff[0] = z.aoff[1] = aoff;
    z.BTz[0] = z.BTz[1] = BT; z.biasz[0] = z.biasz[1] = b; z.Cz[0] = z.Cz[1] = C; return z;
  };
  auto zp2 = [](const void* A0, const void* A1, size_t o0, size_t o1,
                const __bf16* B0, const __bf16* B1, const float* b0, const float* b1,
                void* C0, void* C1) {
    ZP z; z.Az[0] = A0; z.Az[1] = A1; z.aoff[0] = o0; z.aoff[1] = o1;
    z.BTz[0] = B0; z.BTz[1] = B1; z.biasz[0] = b0; z.biasz[1] = b1;
    z.Cz[0] = C0; z.Cz[1] = C1; return z;
  };

  // ---- merged encoders (2 chunks of 4096 rows) ----
  transpose_k<<<dim3(64, 32), b256, 0, stream>>>(Wr1, TAB, 1024, 2048);
  transpose_k<<<dim3(64, 32), b256, 0, stream>>>(Wi1, TAB + 2097152, 1024, 2048);
  transpose_k<<<dim3(16, 64), b256, 0, stream>>>(Wr2, TB2, 2048, 512);
  transpose_k<<<dim3(16, 64), b256, 0, stream>>>(Wi2, TB2 + 1048576, 2048, 512);
  for (int mc = 0; mc < 2; ++mc) {
    cvt_k<<<dim3(2048), b256, 0, stream>>>(x + (size_t)mc * 4194304, xch);
    mgemm_k<1,0,1,1><<<dim3(32, 32, 1), b256, 0, stream>>>(
        zp1(xch, 0, TAB, br1, hLR), bi1, 4096, 4096, 1024, 1024, ni, ni, nf, nf);
    mgemm_k<0,0,0,0><<<dim3(4, 32, 2), b256, 0, stream>>>(
        zp2(hLR, hLR, 0, 2048, TB2, TB2 + 1048576, br2, bi2,
            out + ZR_OFF + (size_t)mc * 2097152, out + ZI_OFF + (size_t)mc * 2097152),
        nf, 4096, 512, 2048, 4096, ni, ni, nf, nf);
  }
  // ---- label encoder (zE in ws; z_label gather deferred) ----
  mgemm_k<1,1,1,0><<<dim3(16, 1, 1), b256, 0, stream>>>(
      zp1(E, 0, TAB, br1, hE), nf, 32, 2048, 1024, 1024, ni, ni, nf, nf);
  mgemm_k<0,0,0,0><<<dim3(4, 1, 1), b256, 0, stream>>>(
      zp1(hE, 0, TB2, br2, zE), nf, 32, 512, 2048, 2048, ni, ni, nf, nf);

  // ---- permutations + per-sample losses (z_label via zE gather in-kernel) ----
  threefry_s_k<<<dim3(32), b256, 0, stream>>>(labels, sval);
  rank_k<<<dim3(256), b256, 0, stream>>>(labels, sval, ordr, prm);
  persample_k<<<dim3(2048), b256, 0, stream>>>(out, zE, labels, costT, psamp);
  group_reduce_k<<<dim3(32), b256, 0, stream>>>(labels, psamp, gmean, present);

  // ---- classifier (hcAll in XR; single L1 pass) ----
  transpose_k<<<dim3(64, 16), b256, 0, stream>>>(Wc1, TAc, 512, 2048);
  transpose_k<<<dim3(1, 64), b256, 0, stream>>>(Wc2, TBc, 2048, 32);
  mgemm_k<0,1,1,0><<<dim3(16, 64, 1), b256, 0, stream>>>(
      zp1(out + ZR_OFF, 0, TAc, bc1, hcAll), nf, 8192, 2048, 512, 512, ni, ni, nf, nf);
  bnacc_k<<<dim3(32, 32), b256, 0, stream>>>(hcAll, bnsum, bnsum2, 0);
  bnfinal_k<<<dim3(8), b256, 0, stream>>>(bnsum, bnsum2, bng, bnb, bnscale, bnshift);
  bnapply_k<<<dim3(8192), b256, 0, stream>>>(hcAll, bnscale, bnshift);
  mgemm_k<0,0,0,0><<<dim3(1, 64, 1), b256, 0, stream>>>(
      zp1(hcAll, 0, TBc, bc2, out + LG_OFF), nf, 8192, 32, 2048, 2048, ni, ni, nf, nf);

  // ---- decoder (2 chunks of 4096; overwrites XR) ----
  transpose_k<<<dim3(64, 32), b256, 0, stream>>>(Wd1, TAd, 1024, 2048);
  transpose_k<<<dim3(32, 64), b256, 0, stream>>>(Wd2, TBd, 2048, 1024);
  for (int mc = 0; mc < 2; ++mc) {
    mgemm_k<1,2,1,0><<<dim3(16, 32, 1), b256, 0, stream>>>(
        zp1(nullptr, (size_t)mc * 4096, TAd, bd1, hb), nf, 4096, 2048, 1024, 0,
        prm, ordr, out + ZR_OFF, out + ZI_OFF);
    mgemm_k<0,0,0,0><<<dim3(8, 32, 1), b256, 0, stream>>>(
        zp1(hb, 0, TBd, bd2, out + XR_OFF + (size_t)mc * 4194304), nf,
        4096, 1024, 2048, 2048, ni, ni, nf, nf);
  }

  // ---- scalar finals, z_label gather, x_ori LAST ----
  ot_reduce_k<<<dim3(1), b256, 0, stream>>>(costT, out);
  contra_final_k<<<dim3(1), dim3(64), 0, stream>>>(gmean, present, out);
  gather512_k<<<dim3(2048), b256, 0, stream>>>(zE, labels, out + ZL_OFF);
  xori_k<<<dim3(8192), dim3(128), 0, stream>>>(x, ordr, out);

  (void)in_sizes; (void)n_in; (void)out_size;
}